// Round 14
// baseline (249.111 us; speedup 1.0000x reference)
//
#include <hip/hip_runtime.h>
#include <hip/hip_bf16.h>

typedef __hip_bfloat16 bf16;
typedef short short8v __attribute__((ext_vector_type(8)));
typedef short short4v __attribute__((ext_vector_type(4)));
typedef float float4v __attribute__((ext_vector_type(4)));

static __device__ __forceinline__ float b2f(bf16 v){ return __bfloat162float(v); }
static __device__ __forceinline__ bf16 f2b(float v){ return __float2bfloat16(v); }
static __device__ __forceinline__ float bu2f(unsigned short u){ return __uint_as_float(((unsigned)u) << 16); }
static __device__ __forceinline__ short f2bs(float v){ bf16 t = __float2bfloat16(v); return *(short*)&t; }

#define WT 128
#define HWT 16384

// ---- packed f32 weights (float offsets inside ws) ----
#define OFF_BZ    20544    // 32
#define OFF_BR    39008    // 32
#define OFF_BQ    57472    // 32
#define OFF_DWP   57504    // [tap][64]        576
#define OFF_DWB   58080    // 64
#define OFF_LNG   58144    // 64
#define OFF_LNB   58208    // 64
#define OFF_OMB   65184    // 108 (+4 zero pad)
#define OFF_WINP  65296    // [c][64]          4096
#define OFF_BINP  69392    // 64
#define OFF_BOUT  73552    // 64
#define NW_TOTAL  73616
#define NBF_ZR    36864    // bf16 fragment-order [t:4][kc:18][ln:64][j:8]
#define NBF_Q     18432    // bf16 fragment-order [t:2][kc:18][ln:64][j:8]
#define NBF_OM    7168     // bf16 fragment-order [wv:7][kc:2][ln:64][j:8]
#define NBF_OUT   4096     // bf16 fragment-order [nt:4][kc:2][ln:64][j:8]
#define NPREP     (NW_TOTAL + NBF_ZR + NBF_Q + NBF_OM + NBF_OUT)
#define NHALO     2064     // 4 imgs * 516 halo pixels
#define NTOT      (NPREP + NHALO)
#define NB_PREPB  556      // ceil(NTOT/256)

// ---- ws byte offsets (end = 21,928,448 B) ----
#define B_WZRB  294912
#define B_WQB   368640
#define B_WOMB  405504
#define B_WOUTB 419840
#define B_HXP   428544     // bf16 [4][130][130][64]  (dead after k_zr)
#define B_QINP  9081344    // bf16 [4][130][130][64]  (dead after stageB)
#define B_ZBUF  17734144   // bf16 [4][128][32][128]
#define B_XL    428544     // bf16 [4][HWT][64] overlays HXP (written in stageB)

// ---------------- K1: stage1 = weight-prep blocks + encoder blocks (merged launch) ----------------
__global__ void __launch_bounds__(256) k_stage1(
    const float* __restrict__ enc_w, const float* __restrict__ enc_b,
    const float* __restrict__ bn_g, const float* __restrict__ bn_b,
    const float* __restrict__ bn_m, const float* __restrict__ bn_v,
    const float* __restrict__ gwz, const float* __restrict__ gbz,
    const float* __restrict__ gwr, const float* __restrict__ gbr,
    const float* __restrict__ gwq, const float* __restrict__ gbq,
    const float* __restrict__ dww, const float* __restrict__ dwb,
    const float* __restrict__ lng, const float* __restrict__ lnb,
    const float* __restrict__ offw, const float* __restrict__ offb,
    const float* __restrict__ maskw, const float* __restrict__ maskb,
    const float* __restrict__ inpw, const float* __restrict__ inpb,
    const float* __restrict__ outw, const float* __restrict__ outb,
    float* __restrict__ Wp, bf16* __restrict__ wzrb, bf16* __restrict__ wqb,
    bf16* __restrict__ womb, bf16* __restrict__ woutb,
    bf16* __restrict__ hxp, bf16* __restrict__ qinp,
    const float* __restrict__ X, const float* __restrict__ Y) {
  __shared__ float xls[4096];
  __shared__ float ewls[2048];
  __shared__ float escl[64];
  int tid = threadIdx.x;
  int b = blockIdx.x;

  if (b < NB_PREPB) {
    int i = b * 256 + tid;
    if (i >= NTOT) return;
    if (i >= NPREP) {
      int t = i - NPREP;
      int img = t / 516, r = t % 516;
      int ph, pw;
      if (r < 130) { ph = 0; pw = r; }
      else if (r < 260) { ph = 129; pw = r - 130; }
      else if (r < 388) { ph = r - 260 + 1; pw = 0; }
      else { ph = r - 388 + 1; pw = 129; }
      size_t pb = (((size_t)img * 130 + ph) * 130 + pw) * 64;
      uint4 zz = make_uint4(0, 0, 0, 0);
      #pragma unroll
      for (int k = 0; k < 8; ++k) {
        ((uint4*)(hxp + pb))[k] = zz;
        ((uint4*)(qinp + pb))[k] = zz;
      }
      return;
    }
    if (i >= NW_TOTAL) {
      int d = i - NW_TOTAL;
      if (d < NBF_ZR) {
        int t = d / 9216, rem = d % 9216;
        int kc = rem / 512, rem2 = rem % 512;
        int ln = rem2 >> 3, j = rem2 & 7;
        int n = t * 16 + (ln & 15);
        int cin = (kc & 1) * 32 + ((ln >> 4) << 3) + j;
        int tap = kc >> 1;
        float v = (n < 32) ? gwz[(n*64 + cin)*9 + tap] : gwr[((n-32)*64 + cin)*9 + tap];
        wzrb[d] = f2b(v);
      } else if (d < NBF_ZR + NBF_Q) {
        int d2 = d - NBF_ZR;
        int t = d2 / 9216, rem = d2 % 9216;
        int kc = rem / 512, rem2 = rem % 512;
        int ln = rem2 >> 3, j = rem2 & 7;
        int n = t * 16 + (ln & 15);
        int cin = (kc & 1) * 32 + ((ln >> 4) << 3) + j;
        int tap = kc >> 1;
        wqb[d2] = f2b(gwq[(n*64 + cin)*9 + tap]);
      } else if (d < NBF_ZR + NBF_Q + NBF_OM) {
        int d3 = d - NBF_ZR - NBF_Q;
        int wv = d3 / 1024, rem = d3 % 1024;
        int kc = rem / 512, rem2 = rem % 512;
        int ln = rem2 >> 3, j = rem2 & 7;
        int jcol = wv * 16 + (ln & 15);
        int c = kc * 32 + ((ln >> 4) << 3) + j;
        float v = (jcol < 72) ? offw[jcol*64 + c] : ((jcol < 108) ? maskw[(jcol-72)*64 + c] : 0.f);
        womb[d3] = f2b(v);
      } else {
        int d4 = d - NBF_ZR - NBF_Q - NBF_OM;
        int nt = d4 / 1024, rem = d4 % 1024;
        int kc = rem / 512, rem2 = rem % 512;
        int ln = rem2 >> 3, j = rem2 & 7;
        int o = nt * 16 + (ln & 15);
        int c = kc * 32 + ((ln >> 4) << 3) + j;
        woutb[d4] = f2b(outw[o*64 + c]);
      }
      return;
    }
    float v;
    if (i < 20544) { v = 0.f; }
    else if (i < 20576) { v = gbz[i - OFF_BZ]; }
    else if (i < 39008) { v = 0.f; }
    else if (i < 39040) { v = gbr[i - OFF_BR]; }
    else if (i < 57472) { v = 0.f; }
    else if (i < 57504) { v = gbq[i - OFF_BQ]; }
    else if (i < 58080) { int d = i - OFF_DWP; int tap = d >> 6, o = d & 63; v = dww[o*9 + tap]; }
    else if (i < 58144) { v = dwb[i - OFF_DWB]; }
    else if (i < 58208) { v = lng[i - OFF_LNG]; }
    else if (i < 58272) { v = lnb[i - OFF_LNB]; }
    else if (i < 65184) { v = 0.f; }
    else if (i < 65292) { int j = i - OFF_OMB; v = (j < 72) ? offb[j] : maskb[j-72]; }
    else if (i < 65296) { v = 0.f; }
    else if (i < 69392) { int d = i - OFF_WINP; int c = d >> 6, o = d & 63; v = inpw[o*64 + c]; }
    else if (i < 69456) { v = inpb[i - OFF_BINP]; }
    else if (i < 73552) { v = 0.f; }
    else { v = outb[i - OFF_BOUT]; }
    Wp[i] = v;
    return;
  }

  // ===== encoder blocks =====
  int pb2 = b - NB_PREPB;
  int img = pb2 >> 8, h = (pb2 >> 1) & 127, w0 = (pb2 & 1) * 64;
  int px = tid & 63, sect = tid >> 6;
  #pragma unroll
  for (int k = 0; k < 8; ++k) {
    int i2 = k * 256 + tid;
    int c = i2 >> 5, o = i2 & 31;
    ewls[i2] = enc_w[o*64 + c];
  }
  if (tid < 32) {
    float sc = bn_g[tid] * rsqrtf(bn_v[tid] + 1e-5f);
    escl[tid] = sc;
    escl[32 + tid] = (enc_b[tid] - bn_m[tid]) * sc + bn_b[tid];
  }
  int hw = h * WT + w0 + px;
  const float* xp = X + (size_t)img * (64 * HWT) + hw;
  #pragma unroll
  for (int i2 = 0; i2 < 16; ++i2) {
    int c = sect * 16 + i2;
    xls[c * 64 + px] = xp[c * HWT];
  }
  const float* yp = Y + (size_t)img * (32 * HWT) + hw;
  bf16 yv[8];
  #pragma unroll
  for (int i2 = 0; i2 < 8; ++i2) yv[i2] = f2b(yp[(sect * 8 + i2) * HWT]);
  size_t pbb = (((size_t)img * 130 + h + 1) * 130 + (w0 + px + 1)) * 64;
  *(uint4*)(hxp + pbb + sect * 8) = *(const uint4*)yv;
  __syncthreads();
  float aen[8];
  #pragma unroll
  for (int o = 0; o < 8; ++o) aen[o] = 0.f;
  for (int k = 0; k < 64; ++k) {
    float a = xls[k * 64 + px];
    const float* we = ewls + k * 32 + sect * 8;
    #pragma unroll
    for (int o = 0; o < 8; ++o) aen[o] += a * we[o];
  }
  bf16 xe[8];
  #pragma unroll
  for (int o = 0; o < 8; ++o) {
    int oo = sect * 8 + o;
    float e = aen[o] * escl[oo] + escl[32 + oo];
    xe[o] = f2b(e / (1.f + __expf(-e)));
  }
  *(uint4*)(hxp + pbb + 32 + sect * 8) = *(const uint4*)xe;
  *(uint4*)(qinp + pbb + 32 + sect * 8) = *(const uint4*)xe;
}

// ---------------- K2: z+r implicit-GEMM, M=32/wave, coalesced B (R11 best) ----------------
__global__ void __launch_bounds__(256) k_zr(
    const float* __restrict__ Wp,
    const bf16* __restrict__ hxp, const bf16* __restrict__ wzrb,
    bf16* __restrict__ qinp, bf16* __restrict__ zbuf) {
  __shared__ short zt[32 * 132];
  __shared__ short ryt[128 * 40];
  int tid = threadIdx.x;
  int wv = tid >> 6, ln = tid & 63;
  int quad = ln >> 4, lm = ln & 15;
  int img = blockIdx.z, h = blockIdx.y;
  int p0 = wv * 32;
  const short* hs = (const short*)hxp;
  const short* ws = (const short*)wzrb;
  size_t rowb = ((size_t)img * 130 + h + 1) * 130;
  const short* ab0 = hs + (rowb + p0 + lm + 1) * 64 + quad * 8;
  const short* ab1 = ab0 + 16 * 64;
  short8v a0[18], a1[18];
  #pragma unroll
  for (int kc = 0; kc < 18; ++kc) {
    const int tap = kc >> 1, cin0 = (kc & 1) * 32;
    const int dd = (tap / 3 - 1) * 130 + (tap % 3 - 1);
    a0[kc] = *(const short8v*)(ab0 + dd * 64 + cin0);
    a1[kc] = *(const short8v*)(ab1 + dd * 64 + cin0);
  }
  float4v acc[8];
  #pragma unroll
  for (int t = 0; t < 8; ++t) acc[t] = (float4v){0.f, 0.f, 0.f, 0.f};
  #pragma unroll
  for (int kc = 0; kc < 18; ++kc) {
    #pragma unroll
    for (int t = 0; t < 4; ++t) {
      short8v b = *(const short8v*)(ws + ((t * 18 + kc) * 64 + ln) * 8);
      acc[t*2]   = __builtin_amdgcn_mfma_f32_16x16x32_bf16(a0[kc], b, acc[t*2], 0, 0, 0);
      acc[t*2+1] = __builtin_amdgcn_mfma_f32_16x16x32_bf16(a1[kc], b, acc[t*2+1], 0, 0, 0);
    }
  }
  #pragma unroll
  for (int mt = 0; mt < 2; ++mt) {
    #pragma unroll
    for (int t = 0; t < 2; ++t) {
      int n = t * 16 + lm;
      float bz = Wp[OFF_BZ + n];
      short zp[4];
      #pragma unroll
      for (int ri = 0; ri < 4; ++ri)
        zp[ri] = f2bs(1.f / (1.f + __expf(-(acc[t*2+mt][ri] + bz))));
      *(short4v*)(zt + n * 132 + p0 + mt * 16 + quad * 4) = *(const short4v*)zp;
    }
  }
  #pragma unroll
  for (int mt = 0; mt < 2; ++mt) {
    #pragma unroll
    for (int t = 2; t < 4; ++t) {
      int c = (t - 2) * 16 + lm;
      float br = Wp[OFF_BR + c];
      #pragma unroll
      for (int ri = 0; ri < 4; ++ri) {
        int px = p0 + mt * 16 + quad * 4 + ri;
        float rv = 1.f / (1.f + __expf(-(acc[t*2+mt][ri] + br)));
        float yy = b2f(hxp[(rowb + px + 1) * 64 + c]);
        ryt[px * 40 + c] = f2bs(rv * yy);
      }
    }
  }
  __syncthreads();
  {
    int n2 = tid >> 3, pq = tid & 7;
    short8v z0 = *(const short8v*)(zt + n2 * 132 + pq * 16);
    short8v z1 = *(const short8v*)(zt + n2 * 132 + pq * 16 + 8);
    short* zo = (short*)zbuf + (((size_t)img * 128 + h) * 32 + n2) * 128 + pq * 16;
    *(short8v*)zo = z0;
    *(short8v*)(zo + 8) = z1;
  }
  {
    int px = tid >> 1, chalf = tid & 1;
    short8v r0 = *(const short8v*)(ryt + px * 40 + chalf * 16);
    short8v r1 = *(const short8v*)(ryt + px * 40 + chalf * 16 + 8);
    short* qo = (short*)qinp + (rowb + px + 1) * 64 + chalf * 16;
    *(short8v*)qo = r0;
    *(short8v*)(qo + 8) = r1;
  }
}

// ---------------- K3: stageB = q-GEMM (2-deep A pipeline) + input-linear (128-px f2 tiles) ----------------
__global__ void __launch_bounds__(256) k_stageB(
    const float* __restrict__ Y, const float* __restrict__ Wp,
    const bf16* __restrict__ qinp, const bf16* __restrict__ wqb,
    const bf16* __restrict__ zbuf, float* __restrict__ outh,
    const float* __restrict__ X, bf16* __restrict__ xl) {
  __shared__ char sm[16896];
  int tid = threadIdx.x;
  int b = blockIdx.x;

  if (b < 512) {
    // ===== q implicit-GEMM M=32/wave, 2-deep A software pipeline + GRU combine =====
    float* hout = (float*)sm;   // [32][132]
    int wv = tid >> 6, ln = tid & 63;
    int quad = ln >> 4, lm = ln & 15;
    int img = b >> 7, h = b & 127;
    int p0 = wv * 32;
    const short* qs = (const short*)qinp;
    const short* ws = (const short*)wqb;
    size_t rowb = ((size_t)img * 130 + h + 1) * 130;
    const short* ab0 = qs + (rowb + p0 + lm + 1) * 64 + quad * 8;
    const short* ab1 = ab0 + 16 * 64;
    float4v acc[4];
    #pragma unroll
    for (int t = 0; t < 4; ++t) acc[t] = (float4v){0.f, 0.f, 0.f, 0.f};
    short8v pa0 = *(const short8v*)(ab0 + ((0/3 - 1) * 130 + (0%3 - 1)) * 64);
    short8v pa1 = *(const short8v*)(ab1 + ((0/3 - 1) * 130 + (0%3 - 1)) * 64);
    #pragma unroll
    for (int kc = 0; kc < 18; ++kc) {
      short8v na0 = pa0, na1 = pa1;
      if (kc < 17) {
        const int tapn = (kc + 1) >> 1, cin0n = ((kc + 1) & 1) * 32;
        const int ddn = (tapn / 3 - 1) * 130 + (tapn % 3 - 1);
        na0 = *(const short8v*)(ab0 + ddn * 64 + cin0n);
        na1 = *(const short8v*)(ab1 + ddn * 64 + cin0n);
      }
      #pragma unroll
      for (int t = 0; t < 2; ++t) {
        short8v bb = *(const short8v*)(ws + ((t * 18 + kc) * 64 + ln) * 8);
        acc[t*2]   = __builtin_amdgcn_mfma_f32_16x16x32_bf16(pa0, bb, acc[t*2], 0, 0, 0);
        acc[t*2+1] = __builtin_amdgcn_mfma_f32_16x16x32_bf16(pa1, bb, acc[t*2+1], 0, 0, 0);
      }
      pa0 = na0; pa1 = na1;
    }
    #pragma unroll
    for (int mt = 0; mt < 2; ++mt) {
      #pragma unroll
      for (int t = 0; t < 2; ++t) {
        int n = t * 16 + lm;
        float bq = Wp[OFF_BQ + n];
        float4 hv;
        hv.x = acc[t*2+mt][0] + bq; hv.y = acc[t*2+mt][1] + bq;
        hv.z = acc[t*2+mt][2] + bq; hv.w = acc[t*2+mt][3] + bq;
        *(float4*)(hout + n * 132 + p0 + mt * 16 + quad * 4) = hv;
      }
    }
    __syncthreads();
    const short* zbb = (const short*)zbuf + ((size_t)img * 128 + h) * 32 * 128;
    #pragma unroll
    for (int r = 0; r < 4; ++r) {
      int n = (tid >> 5) + r * 8;
      int px4 = (tid & 31) * 4;
      float4 hv = *(const float4*)(hout + n * 132 + px4);
      uint2 zz = *(const uint2*)(zbb + n * 128 + px4);
      size_t gb = ((size_t)img * 32 + n) * HWT + h * 128 + px4;
      float4 yv = *(const float4*)(Y + gb);
      float z0 = bu2f((unsigned short)(zz.x & 0xFFFFu)), z1 = bu2f((unsigned short)(zz.x >> 16));
      float z2 = bu2f((unsigned short)(zz.y & 0xFFFFu)), z3 = bu2f((unsigned short)(zz.y >> 16));
      float4 o;
      o.x = (1.f - z0) * yv.x + z0 * tanhf(hv.x);
      o.y = (1.f - z1) * yv.y + z1 * tanhf(hv.y);
      o.z = (1.f - z2) * yv.z + z2 * tanhf(hv.z);
      o.w = (1.f - z3) * yv.w + z3 * tanhf(hv.w);
      *(float4*)(outh + gb) = o;
    }
    return;
  }

  // ===== input linear: 128-px row tile, float2 X loads, bf16 LDS =====
  {
    short* xbls = (short*)sm;   // bf16 [64][128] = 16384 B
    int b2 = b - 512;
    int img = b2 >> 7, h = b2 & 127;
    int wave = tid >> 6, lane = tid & 63;
    const float* xb = X + (size_t)img * (64 * HWT) + h * 128 + 2 * lane;
    #pragma unroll
    for (int i = 0; i < 16; ++i) {
      int c = wave * 16 + i;
      float2 xv = *(const float2*)(xb + (size_t)c * HWT);
      unsigned pk = ((unsigned)(unsigned short)f2bs(xv.y) << 16) | (unsigned short)f2bs(xv.x);
      *(unsigned*)(xbls + c * 128 + 2 * lane) = pk;
    }
    __syncthreads();
    int px = lane + (wave & 1) * 64;      // 0..127
    int oh = (wave >> 1) * 32;            // 0 or 32 (wave-uniform)
    float acc[32];
    #pragma unroll
    for (int o = 0; o < 32; ++o) acc[o] = Wp[OFF_BINP + oh + o];
    for (int k = 0; k < 64; ++k) {
      float a = bu2f((unsigned short)xbls[k * 128 + px]);
      const float* wr = Wp + OFF_WINP + k * 64 + oh;
      #pragma unroll
      for (int o = 0; o < 32; ++o) acc[o] += a * wr[o];
    }
    bf16 ov[32];
    #pragma unroll
    for (int o = 0; o < 32; ++o) ov[o] = f2b(acc[o]);
    bf16* op = xl + ((size_t)img * HWT + h * 128 + px) * 64 + oh;
    ((uint4*)op)[0] = ((const uint4*)ov)[0];
    ((uint4*)op)[1] = ((const uint4*)ov)[1];
    ((uint4*)op)[2] = ((const uint4*)ov)[2];
    ((uint4*)op)[3] = ((const uint4*)ov)[3];
  }
}

// ---------------- K5 mega (512 thr); coalesced B; P5 uses all 8 waves ----------------
#define LDS_PSA  0         // f32 [8][64]      2048
#define LDS_PSB  2048      // f32 [8][64]      2048
#define LDS_STAT 4096      // f32 [64][2]      512
#define LDS_Y    4608      // bf16 [64][72]    9216  (val overlays after P2)
#define LDS_OM   13824     // bf16 [64][114]   14592
#define LDS_TOT  28416

__global__ void __launch_bounds__(512) k_mega(
    const float* __restrict__ Wp, const float* __restrict__ hb,
    const bf16* __restrict__ xl, const bf16* __restrict__ womb,
    const bf16* __restrict__ woutb, float* __restrict__ out0) {
  __shared__ char smem[LDS_TOT];
  float* psa  = (float*)(smem + LDS_PSA);
  float* psb  = (float*)(smem + LDS_PSB);
  float* stat = (float*)(smem + LDS_STAT);
  short* yls  = (short*)(smem + LDS_Y);
  short* omls = (short*)(smem + LDS_OM);
  short* vls  = (short*)(smem + LDS_Y);

  int tid = threadIdx.x;
  int img = blockIdx.z, h = blockIdx.y, w0 = blockIdx.x * 64;

  // ---- P1: depthwise conv, 8 out-ch per thread ----
  int wloc = tid & 63, part = tid >> 6;
  int w = w0 + wloc;
  float yv[8];
  {
    const float* hn = hb + (size_t)img * (32 * HWT);
    #pragma unroll
    for (int i = 0; i < 8; ++i) yv[i] = Wp[OFF_DWB + part*8 + i];
    #pragma unroll
    for (int tap = 0; tap < 9; ++tap) {
      int dy = tap / 3 - 1, dx = tap % 3 - 1;
      int hh = h + dy, ww = w + dx;
      bool ok = ((unsigned)hh < 128u) && ((unsigned)ww < 128u);
      int off = hh * WT + ww;
      #pragma unroll
      for (int j = 0; j < 4; ++j) {
        int cin = part * 4 + j;
        float a = ok ? hn[cin * HWT + off] : 0.f;
        yv[2*j]   += a * Wp[OFF_DWP + tap*64 + part*8 + 2*j];
        yv[2*j+1] += a * Wp[OFF_DWP + tap*64 + part*8 + 2*j+1];
      }
    }
  }
  float lsum = 0.f, lsq = 0.f;
  #pragma unroll
  for (int i = 0; i < 8; ++i) { lsum += yv[i]; lsq += yv[i]*yv[i]; }
  psa[part * 64 + wloc] = lsum;
  psb[part * 64 + wloc] = lsq;
  __syncthreads();
  if (tid < 64) {
    float s = 0.f, q = 0.f;
    #pragma unroll
    for (int p = 0; p < 8; ++p) { s += psa[p*64 + tid]; q += psb[p*64 + tid]; }
    float mu = s * (1.f/64.f);
    float var = q * (1.f/64.f) - mu * mu;
    stat[tid*2] = mu;
    stat[tid*2+1] = rsqrtf(var + 1e-6f);
  }
  __syncthreads();
  {
    float mu = stat[wloc*2], inv = stat[wloc*2+1];
    bf16 tmp[8];
    #pragma unroll
    for (int i = 0; i < 8; ++i) {
      int c = part*8 + i;
      float v = (yv[i] - mu) * inv * Wp[OFF_LNG + c] + Wp[OFF_LNB + c];
      tmp[i] = f2b(0.5f * v * (1.f + erff(v * 0.70710678118654752f)));
    }
    *(short8v*)(yls + wloc*72 + part*8) = *(const short8v*)tmp;
  }
  __syncthreads();

  // ---- P2: MFMA offset/mask linear -> omls (bf16); coalesced B ----
  int wv = tid >> 6, ln = tid & 63, quad = ln >> 4, lm = ln & 15;
  if (wv < 7) {
    const short* wb = (const short*)womb;
    float4v acc[4];
    #pragma unroll
    for (int mt = 0; mt < 4; ++mt) acc[mt] = (float4v){0.f,0.f,0.f,0.f};
    #pragma unroll
    for (int kc = 0; kc < 2; ++kc) {
      short8v b = *(const short8v*)(wb + ((wv * 2 + kc) * 64 + ln) * 8);
      #pragma unroll
      for (int mt = 0; mt < 4; ++mt) {
        short8v a = *(const short8v*)(yls + (mt*16 + lm)*72 + kc*32 + quad*8);
        acc[mt] = __builtin_amdgcn_mfma_f32_16x16x32_bf16(a, b, acc[mt], 0, 0, 0);
      }
    }
    float bias = Wp[OFF_OMB + wv*16 + lm];
    #pragma unroll
    for (int mt = 0; mt < 4; ++mt) {
      #pragma unroll
      for (int ri = 0; ri < 4; ++ri)
        omls[(mt*16 + quad*4 + ri)*114 + wv*16 + lm] = f2bs(acc[mt][ri] + bias);
    }
  }
  __syncthreads();

  // ---- P3+P4: softmax + bilinear gather ----
  {
    int px = tid >> 3, g = (tid >> 1) & 3, half = tid & 1;
    const short* oml = omls + px*114;
    float m[9];
    #pragma unroll
    for (int p = 0; p < 9; ++p) m[p] = bu2f((unsigned short)oml[72 + g*9 + p]);
    float mx = m[0];
    #pragma unroll
    for (int p = 1; p < 9; ++p) mx = fmaxf(mx, m[p]);
    float sum = 0.f;
    #pragma unroll
    for (int p = 0; p < 9; ++p) { m[p] = __expf(m[p] - mx); sum += m[p]; }
    float rs = 1.f / sum;
    int wg = w0 + px;
    const bf16* xn = xl + (size_t)img * (HWT * 64);
    float acc[8];
    #pragma unroll
    for (int i = 0; i < 8; ++i) acc[i] = 0.f;
    for (int p = 0; p < 9; ++p) {
      float bx = (float)(wg + p / 3 - 1);
      float by = (float)(h + p % 3 - 1);
      float ox = bu2f((unsigned short)oml[g*18 + p*2]);
      float oy = bu2f((unsigned short)oml[g*18 + p*2 + 1]);
      float mk = m[p] * rs;
      float pxx = bx + ox, pyy = by + oy;
      float fx = floorf(pxx), fy = floorf(pyy);
      int jx0 = (int)fx, jy0 = (int)fy;
      float wx1 = pxx - fx, wy1 = pyy - fy;
      float wx0 = 1.f - wx1, wy0 = 1.f - wy1;
      int cjx[4] = { jx0, jx0 + 1, jx0, jx0 + 1 };
      int cjy[4] = { jy0, jy0, jy0 + 1, jy0 + 1 };
      float cw[4] = { wx0*wy0, wx1*wy0, wx0*wy1, wx1*wy1 };
      #pragma unroll
      for (int k = 0; k < 4; ++k) {
        if ((unsigned)cjx[k] < 128u && (unsigned)cjy[k] < 128u) {
          float cf = mk * cw[k];
          const bf16* s = xn + (size_t)(cjy[k] * WT + cjx[k]) * 64 + g * 16 + half * 8;
          uint4 u0 = *(const uint4*)(s);
          const unsigned uu[4] = {u0.x,u0.y,u0.z,u0.w};
          #pragma unroll
          for (int q = 0; q < 4; ++q) {
            acc[2*q]     += cf * bu2f((unsigned short)(uu[q] & 0xFFFFu));
            acc[2*q + 1] += cf * bu2f((unsigned short)(uu[q] >> 16));
          }
        }
      }
    }
    bf16 tmp[8];
    #pragma unroll
    for (int i = 0; i < 8; ++i) tmp[i] = f2b(acc[i]);
    *(short8v*)(vls + px*72 + g*16 + half*8) = *(const short8v*)tmp;
  }
  __syncthreads();

  // ---- P5: MFMA output linear + SiLU + NCHW f32 store; 8 waves x 2 tiles ----
  {
    const short* wb = (const short*)woutb;
    #pragma unroll
    for (int s = 0; s < 2; ++s) {
      int tile = wv * 2 + s;
      int nt = tile >> 2, mt = tile & 3;
      float4v acc = (float4v){0.f,0.f,0.f,0.f};
      #pragma unroll
      for (int kc = 0; kc < 2; ++kc) {
        short8v b = *(const short8v*)(wb + ((nt * 2 + kc) * 64 + ln) * 8);
        short8v a = *(const short8v*)(vls + (mt*16 + lm)*72 + kc*32 + quad*8);
        acc = __builtin_amdgcn_mfma_f32_16x16x32_bf16(a, b, acc, 0, 0, 0);
      }
      int ch = nt*16 + lm;
      float bias = Wp[OFF_BOUT + ch];
      float4 v;
      float s0 = acc[0] + bias; v.x = s0 / (1.f + __expf(-s0));
      float s1 = acc[1] + bias; v.y = s1 / (1.f + __expf(-s1));
      float s2 = acc[2] + bias; v.z = s2 / (1.f + __expf(-s2));
      float s3 = acc[3] + bias; v.w = s3 / (1.f + __expf(-s3));
      *(float4*)(out0 + ((size_t)img*64 + ch)*HWT + h*128 + w0 + mt*16 + quad*4) = v;
    }
  }
}

extern "C" void kernel_launch(void* const* d_in, const int* in_sizes, int n_in,
                              void* d_out, int out_size, void* d_ws, size_t ws_size,
                              hipStream_t stream) {
  const float* input_x = (const float*)d_in[0];
  const float* input_y = (const float*)d_in[1];

  float* Wp = (float*)d_ws;
  bf16* WZRB  = (bf16*)((char*)d_ws + B_WZRB);
  bf16* WQB   = (bf16*)((char*)d_ws + B_WQB);
  bf16* WOMB  = (bf16*)((char*)d_ws + B_WOMB);
  bf16* WOUTB = (bf16*)((char*)d_ws + B_WOUTB);
  bf16* HXP   = (bf16*)((char*)d_ws + B_HXP);
  bf16* QINP  = (bf16*)((char*)d_ws + B_QINP);
  bf16* ZBUF  = (bf16*)((char*)d_ws + B_ZBUF);
  bf16* XL    = (bf16*)((char*)d_ws + B_XL);
  float* out0 = (float*)d_out;
  float* outh = (float*)d_out + 4194304;

  k_stage1<<<dim3(NB_PREPB + 1024), dim3(256), 0, stream>>>(
      (const float*)d_in[2], (const float*)d_in[3], (const float*)d_in[4], (const float*)d_in[5],
      (const float*)d_in[6], (const float*)d_in[7], (const float*)d_in[8], (const float*)d_in[9],
      (const float*)d_in[10], (const float*)d_in[11], (const float*)d_in[12], (const float*)d_in[13],
      (const float*)d_in[14], (const float*)d_in[15], (const float*)d_in[16], (const float*)d_in[17],
      (const float*)d_in[18], (const float*)d_in[19], (const float*)d_in[20], (const float*)d_in[21],
      (const float*)d_in[22], (const float*)d_in[23], (const float*)d_in[24], (const float*)d_in[25],
      Wp, WZRB, WQB, WOMB, WOUTB, HXP, QINP, input_x, input_y);
  k_zr<<<dim3(1, 128, 4), dim3(256), 0, stream>>>(Wp, HXP, WZRB, QINP, ZBUF);
  k_stageB<<<dim3(1024), dim3(256), 0, stream>>>(input_y, Wp, QINP, WQB, ZBUF, outh, input_x, XL);
  k_mega<<<dim3(2, 128, 4), dim3(512), 0, stream>>>(Wp, outh, XL, WOMB, WOUTB, out0);
}

// Round 15
// 246.828 us; speedup vs baseline: 1.0092x; 1.0092x over previous
//
#include <hip/hip_runtime.h>
#include <hip/hip_bf16.h>

typedef __hip_bfloat16 bf16;
typedef short short8v __attribute__((ext_vector_type(8)));
typedef short short4v __attribute__((ext_vector_type(4)));
typedef float float4v __attribute__((ext_vector_type(4)));

static __device__ __forceinline__ float b2f(bf16 v){ return __bfloat162float(v); }
static __device__ __forceinline__ bf16 f2b(float v){ return __float2bfloat16(v); }
static __device__ __forceinline__ float bu2f(unsigned short u){ return __uint_as_float(((unsigned)u) << 16); }
static __device__ __forceinline__ short f2bs(float v){ bf16 t = __float2bfloat16(v); return *(short*)&t; }

#define WT 128
#define HWT 16384

// ---- packed f32 weights (float offsets inside ws) ----
#define OFF_BZ    20544    // 32
#define OFF_BR    39008    // 32
#define OFF_BQ    57472    // 32
#define OFF_DWP   57504    // [tap][64]        576
#define OFF_DWB   58080    // 64
#define OFF_LNG   58144    // 64
#define OFF_LNB   58208    // 64
#define OFF_OMB   65184    // 108 (+4 zero pad)
#define OFF_WINP  65296    // [c][64]          4096
#define OFF_BINP  69392    // 64
#define OFF_BOUT  73552    // 64
#define NW_TOTAL  73616
#define NBF_ZR    36864    // bf16 fragment-order [t:4][kc:18][ln:64][j:8]
#define NBF_Q     18432    // bf16 fragment-order [t:2][kc:18][ln:64][j:8]
#define NBF_OM    7168     // bf16 fragment-order [wv:7][kc:2][ln:64][j:8]
#define NBF_OUT   4096     // bf16 fragment-order [nt:4][kc:2][ln:64][j:8]
#define NPREP     (NW_TOTAL + NBF_ZR + NBF_Q + NBF_OM + NBF_OUT)
#define NHALO     2064     // 4 imgs * 516 halo pixels
#define NTOT      (NPREP + NHALO)
#define NB_PREPB  556      // ceil(NTOT/256)

// ---- ws byte offsets (end = 21,928,448 B) ----
#define B_WZRB  294912
#define B_WQB   368640
#define B_WOMB  405504
#define B_WOUTB 419840
#define B_HXP   428544     // bf16 [4][130][130][64]  (dead after k_zr)
#define B_QINP  9081344    // bf16 [4][130][130][64]  (dead after stageB)
#define B_ZBUF  17734144   // bf16 [4][128][32][128]
#define B_XL    428544     // bf16 [4][HWT][64] overlays HXP (written in stageB)

// ---------------- K1: stage1 = weight-prep blocks + encoder blocks (merged launch) ----------------
__global__ void __launch_bounds__(256) k_stage1(
    const float* __restrict__ enc_w, const float* __restrict__ enc_b,
    const float* __restrict__ bn_g, const float* __restrict__ bn_b,
    const float* __restrict__ bn_m, const float* __restrict__ bn_v,
    const float* __restrict__ gwz, const float* __restrict__ gbz,
    const float* __restrict__ gwr, const float* __restrict__ gbr,
    const float* __restrict__ gwq, const float* __restrict__ gbq,
    const float* __restrict__ dww, const float* __restrict__ dwb,
    const float* __restrict__ lng, const float* __restrict__ lnb,
    const float* __restrict__ offw, const float* __restrict__ offb,
    const float* __restrict__ maskw, const float* __restrict__ maskb,
    const float* __restrict__ inpw, const float* __restrict__ inpb,
    const float* __restrict__ outw, const float* __restrict__ outb,
    float* __restrict__ Wp, bf16* __restrict__ wzrb, bf16* __restrict__ wqb,
    bf16* __restrict__ womb, bf16* __restrict__ woutb,
    bf16* __restrict__ hxp, bf16* __restrict__ qinp,
    const float* __restrict__ X, const float* __restrict__ Y) {
  __shared__ float xls[4096];
  __shared__ float ewls[2048];
  __shared__ float escl[64];
  int tid = threadIdx.x;
  int b = blockIdx.x;

  if (b < NB_PREPB) {
    int i = b * 256 + tid;
    if (i >= NTOT) return;
    if (i >= NPREP) {
      int t = i - NPREP;
      int img = t / 516, r = t % 516;
      int ph, pw;
      if (r < 130) { ph = 0; pw = r; }
      else if (r < 260) { ph = 129; pw = r - 130; }
      else if (r < 388) { ph = r - 260 + 1; pw = 0; }
      else { ph = r - 388 + 1; pw = 129; }
      size_t pb = (((size_t)img * 130 + ph) * 130 + pw) * 64;
      uint4 zz = make_uint4(0, 0, 0, 0);
      #pragma unroll
      for (int k = 0; k < 8; ++k) {
        ((uint4*)(hxp + pb))[k] = zz;
        ((uint4*)(qinp + pb))[k] = zz;
      }
      return;
    }
    if (i >= NW_TOTAL) {
      int d = i - NW_TOTAL;
      if (d < NBF_ZR) {
        int t = d / 9216, rem = d % 9216;
        int kc = rem / 512, rem2 = rem % 512;
        int ln = rem2 >> 3, j = rem2 & 7;
        int n = t * 16 + (ln & 15);
        int cin = (kc & 1) * 32 + ((ln >> 4) << 3) + j;
        int tap = kc >> 1;
        float v = (n < 32) ? gwz[(n*64 + cin)*9 + tap] : gwr[((n-32)*64 + cin)*9 + tap];
        wzrb[d] = f2b(v);
      } else if (d < NBF_ZR + NBF_Q) {
        int d2 = d - NBF_ZR;
        int t = d2 / 9216, rem = d2 % 9216;
        int kc = rem / 512, rem2 = rem % 512;
        int ln = rem2 >> 3, j = rem2 & 7;
        int n = t * 16 + (ln & 15);
        int cin = (kc & 1) * 32 + ((ln >> 4) << 3) + j;
        int tap = kc >> 1;
        wqb[d2] = f2b(gwq[(n*64 + cin)*9 + tap]);
      } else if (d < NBF_ZR + NBF_Q + NBF_OM) {
        int d3 = d - NBF_ZR - NBF_Q;
        int wv = d3 / 1024, rem = d3 % 1024;
        int kc = rem / 512, rem2 = rem % 512;
        int ln = rem2 >> 3, j = rem2 & 7;
        int jcol = wv * 16 + (ln & 15);
        int c = kc * 32 + ((ln >> 4) << 3) + j;
        float v = (jcol < 72) ? offw[jcol*64 + c] : ((jcol < 108) ? maskw[(jcol-72)*64 + c] : 0.f);
        womb[d3] = f2b(v);
      } else {
        int d4 = d - NBF_ZR - NBF_Q - NBF_OM;
        int nt = d4 / 1024, rem = d4 % 1024;
        int kc = rem / 512, rem2 = rem % 512;
        int ln = rem2 >> 3, j = rem2 & 7;
        int o = nt * 16 + (ln & 15);
        int c = kc * 32 + ((ln >> 4) << 3) + j;
        woutb[d4] = f2b(outw[o*64 + c]);
      }
      return;
    }
    float v;
    if (i < 20544) { v = 0.f; }
    else if (i < 20576) { v = gbz[i - OFF_BZ]; }
    else if (i < 39008) { v = 0.f; }
    else if (i < 39040) { v = gbr[i - OFF_BR]; }
    else if (i < 57472) { v = 0.f; }
    else if (i < 57504) { v = gbq[i - OFF_BQ]; }
    else if (i < 58080) { int d = i - OFF_DWP; int tap = d >> 6, o = d & 63; v = dww[o*9 + tap]; }
    else if (i < 58144) { v = dwb[i - OFF_DWB]; }
    else if (i < 58208) { v = lng[i - OFF_LNG]; }
    else if (i < 58272) { v = lnb[i - OFF_LNB]; }
    else if (i < 65184) { v = 0.f; }
    else if (i < 65292) { int j = i - OFF_OMB; v = (j < 72) ? offb[j] : maskb[j-72]; }
    else if (i < 65296) { v = 0.f; }
    else if (i < 69392) { int d = i - OFF_WINP; int c = d >> 6, o = d & 63; v = inpw[o*64 + c]; }
    else if (i < 69456) { v = inpb[i - OFF_BINP]; }
    else if (i < 73552) { v = 0.f; }
    else { v = outb[i - OFF_BOUT]; }
    Wp[i] = v;
    return;
  }

  // ===== encoder blocks =====
  int pb2 = b - NB_PREPB;
  int img = pb2 >> 8, h = (pb2 >> 1) & 127, w0 = (pb2 & 1) * 64;
  int px = tid & 63, sect = tid >> 6;
  #pragma unroll
  for (int k = 0; k < 8; ++k) {
    int i2 = k * 256 + tid;
    int c = i2 >> 5, o = i2 & 31;
    ewls[i2] = enc_w[o*64 + c];
  }
  if (tid < 32) {
    float sc = bn_g[tid] * rsqrtf(bn_v[tid] + 1e-5f);
    escl[tid] = sc;
    escl[32 + tid] = (enc_b[tid] - bn_m[tid]) * sc + bn_b[tid];
  }
  int hw = h * WT + w0 + px;
  const float* xp = X + (size_t)img * (64 * HWT) + hw;
  #pragma unroll
  for (int i2 = 0; i2 < 16; ++i2) {
    int c = sect * 16 + i2;
    xls[c * 64 + px] = xp[c * HWT];
  }
  const float* yp = Y + (size_t)img * (32 * HWT) + hw;
  bf16 yv[8];
  #pragma unroll
  for (int i2 = 0; i2 < 8; ++i2) yv[i2] = f2b(yp[(sect * 8 + i2) * HWT]);
  size_t pbb = (((size_t)img * 130 + h + 1) * 130 + (w0 + px + 1)) * 64;
  *(uint4*)(hxp + pbb + sect * 8) = *(const uint4*)yv;
  __syncthreads();
  float aen[8];
  #pragma unroll
  for (int o = 0; o < 8; ++o) aen[o] = 0.f;
  for (int k = 0; k < 64; ++k) {
    float a = xls[k * 64 + px];
    const float* we = ewls + k * 32 + sect * 8;
    #pragma unroll
    for (int o = 0; o < 8; ++o) aen[o] += a * we[o];
  }
  bf16 xe[8];
  #pragma unroll
  for (int o = 0; o < 8; ++o) {
    int oo = sect * 8 + o;
    float e = aen[o] * escl[oo] + escl[32 + oo];
    xe[o] = f2b(e / (1.f + __expf(-e)));
  }
  *(uint4*)(hxp + pbb + 32 + sect * 8) = *(const uint4*)xe;
  *(uint4*)(qinp + pbb + 32 + sect * 8) = *(const uint4*)xe;
}

// ---------------- K2: z+r implicit-GEMM, M=32/wave, coalesced B (R11 best) ----------------
__global__ void __launch_bounds__(256) k_zr(
    const float* __restrict__ Wp,
    const bf16* __restrict__ hxp, const bf16* __restrict__ wzrb,
    bf16* __restrict__ qinp, bf16* __restrict__ zbuf) {
  __shared__ short zt[32 * 132];
  __shared__ short ryt[128 * 40];
  int tid = threadIdx.x;
  int wv = tid >> 6, ln = tid & 63;
  int quad = ln >> 4, lm = ln & 15;
  int img = blockIdx.z, h = blockIdx.y;
  int p0 = wv * 32;
  const short* hs = (const short*)hxp;
  const short* ws = (const short*)wzrb;
  size_t rowb = ((size_t)img * 130 + h + 1) * 130;
  const short* ab0 = hs + (rowb + p0 + lm + 1) * 64 + quad * 8;
  const short* ab1 = ab0 + 16 * 64;
  short8v a0[18], a1[18];
  #pragma unroll
  for (int kc = 0; kc < 18; ++kc) {
    const int tap = kc >> 1, cin0 = (kc & 1) * 32;
    const int dd = (tap / 3 - 1) * 130 + (tap % 3 - 1);
    a0[kc] = *(const short8v*)(ab0 + dd * 64 + cin0);
    a1[kc] = *(const short8v*)(ab1 + dd * 64 + cin0);
  }
  float4v acc[8];
  #pragma unroll
  for (int t = 0; t < 8; ++t) acc[t] = (float4v){0.f, 0.f, 0.f, 0.f};
  #pragma unroll
  for (int kc = 0; kc < 18; ++kc) {
    #pragma unroll
    for (int t = 0; t < 4; ++t) {
      short8v b = *(const short8v*)(ws + ((t * 18 + kc) * 64 + ln) * 8);
      acc[t*2]   = __builtin_amdgcn_mfma_f32_16x16x32_bf16(a0[kc], b, acc[t*2], 0, 0, 0);
      acc[t*2+1] = __builtin_amdgcn_mfma_f32_16x16x32_bf16(a1[kc], b, acc[t*2+1], 0, 0, 0);
    }
  }
  #pragma unroll
  for (int mt = 0; mt < 2; ++mt) {
    #pragma unroll
    for (int t = 0; t < 2; ++t) {
      int n = t * 16 + lm;
      float bz = Wp[OFF_BZ + n];
      short zp[4];
      #pragma unroll
      for (int ri = 0; ri < 4; ++ri)
        zp[ri] = f2bs(1.f / (1.f + __expf(-(acc[t*2+mt][ri] + bz))));
      *(short4v*)(zt + n * 132 + p0 + mt * 16 + quad * 4) = *(const short4v*)zp;
    }
  }
  #pragma unroll
  for (int mt = 0; mt < 2; ++mt) {
    #pragma unroll
    for (int t = 2; t < 4; ++t) {
      int c = (t - 2) * 16 + lm;
      float br = Wp[OFF_BR + c];
      #pragma unroll
      for (int ri = 0; ri < 4; ++ri) {
        int px = p0 + mt * 16 + quad * 4 + ri;
        float rv = 1.f / (1.f + __expf(-(acc[t*2+mt][ri] + br)));
        float yy = b2f(hxp[(rowb + px + 1) * 64 + c]);
        ryt[px * 40 + c] = f2bs(rv * yy);
      }
    }
  }
  __syncthreads();
  {
    int n2 = tid >> 3, pq = tid & 7;
    short8v z0 = *(const short8v*)(zt + n2 * 132 + pq * 16);
    short8v z1 = *(const short8v*)(zt + n2 * 132 + pq * 16 + 8);
    short* zo = (short*)zbuf + (((size_t)img * 128 + h) * 32 + n2) * 128 + pq * 16;
    *(short8v*)zo = z0;
    *(short8v*)(zo + 8) = z1;
  }
  {
    int px = tid >> 1, chalf = tid & 1;
    short8v r0 = *(const short8v*)(ryt + px * 40 + chalf * 16);
    short8v r1 = *(const short8v*)(ryt + px * 40 + chalf * 16 + 8);
    short* qo = (short*)qinp + (rowb + px + 1) * 64 + chalf * 16;
    *(short8v*)qo = r0;
    *(short8v*)(qo + 8) = r1;
  }
}

// ---------------- K3: stageB = q-GEMM+combine blocks + input-linear blocks (R13 form) ----------------
__global__ void __launch_bounds__(256) k_stageB(
    const float* __restrict__ Y, const float* __restrict__ Wp,
    const bf16* __restrict__ qinp, const bf16* __restrict__ wqb,
    const bf16* __restrict__ zbuf, float* __restrict__ outh,
    const float* __restrict__ X, bf16* __restrict__ xl) {
  __shared__ char sm[16896];
  int tid = threadIdx.x;
  int b = blockIdx.x;

  if (b < 512) {
    float* hout = (float*)sm;   // [32][132]
    int wv = tid >> 6, ln = tid & 63;
    int quad = ln >> 4, lm = ln & 15;
    int img = b >> 7, h = b & 127;
    int p0 = wv * 32;
    const short* qs = (const short*)qinp;
    const short* ws = (const short*)wqb;
    size_t rowb = ((size_t)img * 130 + h + 1) * 130;
    const short* ab0 = qs + (rowb + p0 + lm + 1) * 64 + quad * 8;
    const short* ab1 = ab0 + 16 * 64;
    float4v acc[4];
    #pragma unroll
    for (int t = 0; t < 4; ++t) acc[t] = (float4v){0.f, 0.f, 0.f, 0.f};
    #pragma unroll
    for (int kc = 0; kc < 18; ++kc) {
      const int tap = kc >> 1, cin0 = (kc & 1) * 32;
      const int dd = (tap / 3 - 1) * 130 + (tap % 3 - 1);
      short8v a0 = *(const short8v*)(ab0 + dd * 64 + cin0);
      short8v a1 = *(const short8v*)(ab1 + dd * 64 + cin0);
      #pragma unroll
      for (int t = 0; t < 2; ++t) {
        short8v bb = *(const short8v*)(ws + ((t * 18 + kc) * 64 + ln) * 8);
        acc[t*2]   = __builtin_amdgcn_mfma_f32_16x16x32_bf16(a0, bb, acc[t*2], 0, 0, 0);
        acc[t*2+1] = __builtin_amdgcn_mfma_f32_16x16x32_bf16(a1, bb, acc[t*2+1], 0, 0, 0);
      }
    }
    #pragma unroll
    for (int mt = 0; mt < 2; ++mt) {
      #pragma unroll
      for (int t = 0; t < 2; ++t) {
        int n = t * 16 + lm;
        float bq = Wp[OFF_BQ + n];
        float4 hv;
        hv.x = acc[t*2+mt][0] + bq; hv.y = acc[t*2+mt][1] + bq;
        hv.z = acc[t*2+mt][2] + bq; hv.w = acc[t*2+mt][3] + bq;
        *(float4*)(hout + n * 132 + p0 + mt * 16 + quad * 4) = hv;
      }
    }
    __syncthreads();
    const short* zbb = (const short*)zbuf + ((size_t)img * 128 + h) * 32 * 128;
    #pragma unroll
    for (int r = 0; r < 4; ++r) {
      int n = (tid >> 5) + r * 8;
      int px4 = (tid & 31) * 4;
      float4 hv = *(const float4*)(hout + n * 132 + px4);
      uint2 zz = *(const uint2*)(zbb + n * 128 + px4);
      size_t gb = ((size_t)img * 32 + n) * HWT + h * 128 + px4;
      float4 yv = *(const float4*)(Y + gb);
      float z0 = bu2f((unsigned short)(zz.x & 0xFFFFu)), z1 = bu2f((unsigned short)(zz.x >> 16));
      float z2 = bu2f((unsigned short)(zz.y & 0xFFFFu)), z3 = bu2f((unsigned short)(zz.y >> 16));
      float4 o;
      o.x = (1.f - z0) * yv.x + z0 * tanhf(hv.x);
      o.y = (1.f - z1) * yv.y + z1 * tanhf(hv.y);
      o.z = (1.f - z2) * yv.z + z2 * tanhf(hv.z);
      o.w = (1.f - z3) * yv.w + z3 * tanhf(hv.w);
      *(float4*)(outh + gb) = o;
    }
    return;
  }

  // ===== input linear via LDS x-tile =====
  {
    float* xls = (float*)sm;    // 4096 floats
    int b2 = b - 512;
    int px = tid & 63, sect = tid >> 6;
    int img = b2 >> 8, h = (b2 >> 1) & 127, w0 = (b2 & 1) * 64;
    int hw = h * WT + w0 + px;
    const float* xp = X + (size_t)img * (64 * HWT) + hw;
    #pragma unroll
    for (int i = 0; i < 16; ++i) {
      int c = sect * 16 + i;
      xls[c * 64 + px] = xp[c * HWT];
    }
    __syncthreads();
    float acc[16];
    #pragma unroll
    for (int o = 0; o < 16; ++o) acc[o] = Wp[OFF_BINP + sect * 16 + o];
    for (int k = 0; k < 64; ++k) {
      float a = xls[k * 64 + px];
      const float* wr = Wp + OFF_WINP + k * 64 + sect * 16;
      #pragma unroll
      for (int o = 0; o < 16; ++o) acc[o] += a * wr[o];
    }
    bf16 ov[16];
    #pragma unroll
    for (int o = 0; o < 16; ++o) ov[o] = f2b(acc[o]);
    bf16* op = xl + ((size_t)img * HWT + hw) * 64 + sect * 16;
    ((uint4*)op)[0] = ((const uint4*)ov)[0];
    ((uint4*)op)[1] = ((const uint4*)ov)[1];
  }
}

// ---------------- K5 mega: 32-px tiles, 256 thr, grid 2048 (phase-drain overlap) ----------------
#define LDS_PSA  0         // f32 [8][32]      1024
#define LDS_PSB  1024      // f32 [8][32]      1024
#define LDS_STAT 2048      // f32 [32][2]      256
#define LDS_Y    2304      // bf16 [32][72]    4608  (vls overlays after P2)
#define LDS_OM   6912      // bf16 [32][114]   7296
#define LDS_TOT  14208

__global__ void __launch_bounds__(256) k_mega(
    const float* __restrict__ Wp, const float* __restrict__ hb,
    const bf16* __restrict__ xl, const bf16* __restrict__ womb,
    const bf16* __restrict__ woutb, float* __restrict__ out0) {
  __shared__ char smem[LDS_TOT];
  float* psa  = (float*)(smem + LDS_PSA);
  float* psb  = (float*)(smem + LDS_PSB);
  float* stat = (float*)(smem + LDS_STAT);
  short* yls  = (short*)(smem + LDS_Y);
  short* omls = (short*)(smem + LDS_OM);
  short* vls  = (short*)(smem + LDS_Y);

  int tid = threadIdx.x;
  int img = blockIdx.z, h = blockIdx.y, w0 = blockIdx.x * 32;

  // ---- P1: depthwise conv, 8 out-ch per thread, 32 px ----
  int wloc = tid & 31, part = tid >> 5;     // part 0..7
  int w = w0 + wloc;
  float yv[8];
  {
    const float* hn = hb + (size_t)img * (32 * HWT);
    #pragma unroll
    for (int i = 0; i < 8; ++i) yv[i] = Wp[OFF_DWB + part*8 + i];
    #pragma unroll
    for (int tap = 0; tap < 9; ++tap) {
      int dy = tap / 3 - 1, dx = tap % 3 - 1;
      int hh = h + dy, ww = w + dx;
      bool ok = ((unsigned)hh < 128u) && ((unsigned)ww < 128u);
      int off = hh * WT + ww;
      #pragma unroll
      for (int j = 0; j < 4; ++j) {
        int cin = part * 4 + j;
        float a = ok ? hn[cin * HWT + off] : 0.f;
        yv[2*j]   += a * Wp[OFF_DWP + tap*64 + part*8 + 2*j];
        yv[2*j+1] += a * Wp[OFF_DWP + tap*64 + part*8 + 2*j+1];
      }
    }
  }
  float lsum = 0.f, lsq = 0.f;
  #pragma unroll
  for (int i = 0; i < 8; ++i) { lsum += yv[i]; lsq += yv[i]*yv[i]; }
  psa[part * 32 + wloc] = lsum;
  psb[part * 32 + wloc] = lsq;
  __syncthreads();
  if (tid < 32) {
    float s = 0.f, q = 0.f;
    #pragma unroll
    for (int p = 0; p < 8; ++p) { s += psa[p*32 + tid]; q += psb[p*32 + tid]; }
    float mu = s * (1.f/64.f);
    float var = q * (1.f/64.f) - mu * mu;
    stat[tid*2] = mu;
    stat[tid*2+1] = rsqrtf(var + 1e-6f);
  }
  __syncthreads();
  {
    float mu = stat[wloc*2], inv = stat[wloc*2+1];
    bf16 tmp[8];
    #pragma unroll
    for (int i = 0; i < 8; ++i) {
      int c = part*8 + i;
      float v = (yv[i] - mu) * inv * Wp[OFF_LNG + c] + Wp[OFF_LNB + c];
      tmp[i] = f2b(0.5f * v * (1.f + erff(v * 0.70710678118654752f)));
    }
    *(short8v*)(yls + wloc*72 + part*8) = *(const short8v*)tmp;
  }
  __syncthreads();

  // ---- P2: MFMA offset/mask linear -> omls (bf16); 14 tiles over 4 waves ----
  int wv = tid >> 6, ln = tid & 63, quad = ln >> 4, lm = ln & 15;
  {
    const short* wb = (const short*)womb;
    #pragma unroll
    for (int s = 0; s < 4; ++s) {
      int tile = wv + s * 4;
      if (tile < 14) {
        int mt = tile / 7, nt = tile % 7;
        float4v acc = (float4v){0.f,0.f,0.f,0.f};
        #pragma unroll
        for (int kc = 0; kc < 2; ++kc) {
          short8v b = *(const short8v*)(wb + ((nt * 2 + kc) * 64 + ln) * 8);
          short8v a = *(const short8v*)(yls + (mt*16 + lm)*72 + kc*32 + quad*8);
          acc = __builtin_amdgcn_mfma_f32_16x16x32_bf16(a, b, acc, 0, 0, 0);
        }
        float bias = Wp[OFF_OMB + nt*16 + lm];
        #pragma unroll
        for (int ri = 0; ri < 4; ++ri)
          omls[(mt*16 + quad*4 + ri)*114 + nt*16 + lm] = f2bs(acc[ri] + bias);
      }
    }
  }
  __syncthreads();

  // ---- P3+P4: softmax + bilinear gather, thread = (px:32, g:4, half:2) ----
  {
    int px = tid >> 3, g = (tid >> 1) & 3, half = tid & 1;
    const short* oml = omls + px*114;
    float m[9];
    #pragma unroll
    for (int p = 0; p < 9; ++p) m[p] = bu2f((unsigned short)oml[72 + g*9 + p]);
    float mx = m[0];
    #pragma unroll
    for (int p = 1; p < 9; ++p) mx = fmaxf(mx, m[p]);
    float sum = 0.f;
    #pragma unroll
    for (int p = 0; p < 9; ++p) { m[p] = __expf(m[p] - mx); sum += m[p]; }
    float rs = 1.f / sum;
    int wg = w0 + px;
    const bf16* xn = xl + (size_t)img * (HWT * 64);
    float acc[8];
    #pragma unroll
    for (int i = 0; i < 8; ++i) acc[i] = 0.f;
    for (int p = 0; p < 9; ++p) {
      float bx = (float)(wg + p / 3 - 1);
      float by = (float)(h + p % 3 - 1);
      float ox = bu2f((unsigned short)oml[g*18 + p*2]);
      float oy = bu2f((unsigned short)oml[g*18 + p*2 + 1]);
      float mk = m[p] * rs;
      float pxx = bx + ox, pyy = by + oy;
      float fx = floorf(pxx), fy = floorf(pyy);
      int jx0 = (int)fx, jy0 = (int)fy;
      float wx1 = pxx - fx, wy1 = pyy - fy;
      float wx0 = 1.f - wx1, wy0 = 1.f - wy1;
      int cjx[4] = { jx0, jx0 + 1, jx0, jx0 + 1 };
      int cjy[4] = { jy0, jy0, jy0 + 1, jy0 + 1 };
      float cw[4] = { wx0*wy0, wx1*wy0, wx0*wy1, wx1*wy1 };
      #pragma unroll
      for (int k = 0; k < 4; ++k) {
        if ((unsigned)cjx[k] < 128u && (unsigned)cjy[k] < 128u) {
          float cf = mk * cw[k];
          const bf16* s = xn + (size_t)(cjy[k] * WT + cjx[k]) * 64 + g * 16 + half * 8;
          uint4 u0 = *(const uint4*)(s);
          const unsigned uu[4] = {u0.x,u0.y,u0.z,u0.w};
          #pragma unroll
          for (int q = 0; q < 4; ++q) {
            acc[2*q]     += cf * bu2f((unsigned short)(uu[q] & 0xFFFFu));
            acc[2*q + 1] += cf * bu2f((unsigned short)(uu[q] >> 16));
          }
        }
      }
    }
    bf16 tmp[8];
    #pragma unroll
    for (int i = 0; i < 8; ++i) tmp[i] = f2b(acc[i]);
    *(short8v*)(vls + px*72 + g*16 + half*8) = *(const short8v*)tmp;
  }
  __syncthreads();

  // ---- P5: MFMA output linear + SiLU + NCHW f32 store; 8 tiles = 4 waves x 2 ----
  {
    const short* wb = (const short*)woutb;
    #pragma unroll
    for (int s = 0; s < 2; ++s) {
      int tile = wv * 2 + s;
      int nt = tile >> 1, mt = tile & 1;
      float4v acc = (float4v){0.f,0.f,0.f,0.f};
      #pragma unroll
      for (int kc = 0; kc < 2; ++kc) {
        short8v b = *(const short8v*)(wb + ((nt * 2 + kc) * 64 + ln) * 8);
        short8v a = *(const short8v*)(vls + (mt*16 + lm)*72 + kc*32 + quad*8);
        acc = __builtin_amdgcn_mfma_f32_16x16x32_bf16(a, b, acc, 0, 0, 0);
      }
      int ch = nt*16 + lm;
      float bias = Wp[OFF_BOUT + ch];
      float4 v;
      float s0 = acc[0] + bias; v.x = s0 / (1.f + __expf(-s0));
      float s1 = acc[1] + bias; v.y = s1 / (1.f + __expf(-s1));
      float s2 = acc[2] + bias; v.z = s2 / (1.f + __expf(-s2));
      float s3 = acc[3] + bias; v.w = s3 / (1.f + __expf(-s3));
      *(float4*)(out0 + ((size_t)img*64 + ch)*HWT + h*128 + w0 + mt*16 + quad*4) = v;
    }
  }
}

extern "C" void kernel_launch(void* const* d_in, const int* in_sizes, int n_in,
                              void* d_out, int out_size, void* d_ws, size_t ws_size,
                              hipStream_t stream) {
  const float* input_x = (const float*)d_in[0];
  const float* input_y = (const float*)d_in[1];

  float* Wp = (float*)d_ws;
  bf16* WZRB  = (bf16*)((char*)d_ws + B_WZRB);
  bf16* WQB   = (bf16*)((char*)d_ws + B_WQB);
  bf16* WOMB  = (bf16*)((char*)d_ws + B_WOMB);
  bf16* WOUTB = (bf16*)((char*)d_ws + B_WOUTB);
  bf16* HXP   = (bf16*)((char*)d_ws + B_HXP);
  bf16* QINP  = (bf16*)((char*)d_ws + B_QINP);
  bf16* ZBUF  = (bf16*)((char*)d_ws + B_ZBUF);
  bf16* XL    = (bf16*)((char*)d_ws + B_XL);
  float* out0 = (float*)d_out;
  float* outh = (float*)d_out + 4194304;

  k_stage1<<<dim3(NB_PREPB + 1024), dim3(256), 0, stream>>>(
      (const float*)d_in[2], (const float*)d_in[3], (const float*)d_in[4], (const float*)d_in[5],
      (const float*)d_in[6], (const float*)d_in[7], (const float*)d_in[8], (const float*)d_in[9],
      (const float*)d_in[10], (const float*)d_in[11], (const float*)d_in[12], (const float*)d_in[13],
      (const float*)d_in[14], (const float*)d_in[15], (const float*)d_in[16], (const float*)d_in[17],
      (const float*)d_in[18], (const float*)d_in[19], (const float*)d_in[20], (const float*)d_in[21],
      (const float*)d_in[22], (const float*)d_in[23], (const float*)d_in[24], (const float*)d_in[25],
      Wp, WZRB, WQB, WOMB, WOUTB, HXP, QINP, input_x, input_y);
  k_zr<<<dim3(1, 128, 4), dim3(256), 0, stream>>>(Wp, HXP, WZRB, QINP, ZBUF);
  k_stageB<<<dim3(1536), dim3(256), 0, stream>>>(input_y, Wp, QINP, WQB, ZBUF, outh, input_x, XL);
  k_mega<<<dim3(4, 128, 4), dim3(256), 0, stream>>>(Wp, outh, XL, WOMB, WOUTB, out0);
}

// Round 16
// 243.846 us; speedup vs baseline: 1.0216x; 1.0122x over previous
//
#include <hip/hip_runtime.h>
#include <hip/hip_bf16.h>

typedef __hip_bfloat16 bf16;
typedef short short8v __attribute__((ext_vector_type(8)));
typedef short short4v __attribute__((ext_vector_type(4)));
typedef float float4v __attribute__((ext_vector_type(4)));

static __device__ __forceinline__ float b2f(bf16 v){ return __bfloat162float(v); }
static __device__ __forceinline__ bf16 f2b(float v){ return __float2bfloat16(v); }
static __device__ __forceinline__ float bu2f(unsigned short u){ return __uint_as_float(((unsigned)u) << 16); }
static __device__ __forceinline__ short f2bs(float v){ bf16 t = __float2bfloat16(v); return *(short*)&t; }

#define WT 128
#define HWT 16384

// ---- packed f32 weights (float offsets inside ws) ----
#define OFF_BZ    20544    // 32
#define OFF_BR    39008    // 32
#define OFF_BQ    57472    // 32
#define OFF_DWP   57504    // [tap][64]        576
#define OFF_DWB   58080    // 64
#define OFF_LNG   58144    // 64
#define OFF_LNB   58208    // 64
#define OFF_OMB   65184    // 108 (+4 zero pad)
#define OFF_WINP  65296    // [c][64]          4096
#define OFF_BINP  69392    // 64
#define OFF_BOUT  73552    // 64
#define NW_TOTAL  73616
#define NBF_ZR    36864    // bf16 fragment-order [t:4][kc:18][ln:64][j:8]
#define NBF_Q     18432    // bf16 fragment-order [t:2][kc:18][ln:64][j:8]
#define NBF_OM    7168     // bf16 fragment-order [wv:7][kc:2][ln:64][j:8]
#define NBF_OUT   4096     // bf16 fragment-order [nt:4][kc:2][ln:64][j:8]
#define NPREP     (NW_TOTAL + NBF_ZR + NBF_Q + NBF_OM + NBF_OUT)
#define NHALO     2064     // 4 imgs * 516 halo pixels
#define NTOT      (NPREP + NHALO)
#define NB_PREPB  556      // ceil(NTOT/256)

// ---- ws byte offsets (end = 30,317,056 B) ----
#define B_WZRB  294912
#define B_WQB   368640
#define B_WOMB  405504
#define B_WOUTB 419840
#define B_HXP   428544     // bf16 [4][130][130][64]  (dead after zr stage)
#define B_QINP  9081344    // bf16 [4][130][130][64]  (dead after stageB)
#define B_ZBUF  17734144   // bf16 [4][128][32][128]
#define B_XL    21928448   // bf16 [4][HWT][64]  (own region; halves written in zr stage & stageB)

// ---------------- K1: stage1 = weight-prep blocks + encoder blocks (merged launch) ----------------
__global__ void __launch_bounds__(256) k_stage1(
    const float* __restrict__ enc_w, const float* __restrict__ enc_b,
    const float* __restrict__ bn_g, const float* __restrict__ bn_b,
    const float* __restrict__ bn_m, const float* __restrict__ bn_v,
    const float* __restrict__ gwz, const float* __restrict__ gbz,
    const float* __restrict__ gwr, const float* __restrict__ gbr,
    const float* __restrict__ gwq, const float* __restrict__ gbq,
    const float* __restrict__ dww, const float* __restrict__ dwb,
    const float* __restrict__ lng, const float* __restrict__ lnb,
    const float* __restrict__ offw, const float* __restrict__ offb,
    const float* __restrict__ maskw, const float* __restrict__ maskb,
    const float* __restrict__ inpw, const float* __restrict__ inpb,
    const float* __restrict__ outw, const float* __restrict__ outb,
    float* __restrict__ Wp, bf16* __restrict__ wzrb, bf16* __restrict__ wqb,
    bf16* __restrict__ womb, bf16* __restrict__ woutb,
    bf16* __restrict__ hxp, bf16* __restrict__ qinp,
    const float* __restrict__ X, const float* __restrict__ Y) {
  __shared__ float xls[4096];
  __shared__ float ewls[2048];
  __shared__ float escl[64];
  int tid = threadIdx.x;
  int b = blockIdx.x;

  if (b < NB_PREPB) {
    int i = b * 256 + tid;
    if (i >= NTOT) return;
    if (i >= NPREP) {
      int t = i - NPREP;
      int img = t / 516, r = t % 516;
      int ph, pw;
      if (r < 130) { ph = 0; pw = r; }
      else if (r < 260) { ph = 129; pw = r - 130; }
      else if (r < 388) { ph = r - 260 + 1; pw = 0; }
      else { ph = r - 388 + 1; pw = 129; }
      size_t pb = (((size_t)img * 130 + ph) * 130 + pw) * 64;
      uint4 zz = make_uint4(0, 0, 0, 0);
      #pragma unroll
      for (int k = 0; k < 8; ++k) {
        ((uint4*)(hxp + pb))[k] = zz;
        ((uint4*)(qinp + pb))[k] = zz;
      }
      return;
    }
    if (i >= NW_TOTAL) {
      int d = i - NW_TOTAL;
      if (d < NBF_ZR) {
        int t = d / 9216, rem = d % 9216;
        int kc = rem / 512, rem2 = rem % 512;
        int ln = rem2 >> 3, j = rem2 & 7;
        int n = t * 16 + (ln & 15);
        int cin = (kc & 1) * 32 + ((ln >> 4) << 3) + j;
        int tap = kc >> 1;
        float v = (n < 32) ? gwz[(n*64 + cin)*9 + tap] : gwr[((n-32)*64 + cin)*9 + tap];
        wzrb[d] = f2b(v);
      } else if (d < NBF_ZR + NBF_Q) {
        int d2 = d - NBF_ZR;
        int t = d2 / 9216, rem = d2 % 9216;
        int kc = rem / 512, rem2 = rem % 512;
        int ln = rem2 >> 3, j = rem2 & 7;
        int n = t * 16 + (ln & 15);
        int cin = (kc & 1) * 32 + ((ln >> 4) << 3) + j;
        int tap = kc >> 1;
        wqb[d2] = f2b(gwq[(n*64 + cin)*9 + tap]);
      } else if (d < NBF_ZR + NBF_Q + NBF_OM) {
        int d3 = d - NBF_ZR - NBF_Q;
        int wv = d3 / 1024, rem = d3 % 1024;
        int kc = rem / 512, rem2 = rem % 512;
        int ln = rem2 >> 3, j = rem2 & 7;
        int jcol = wv * 16 + (ln & 15);
        int c = kc * 32 + ((ln >> 4) << 3) + j;
        float v = (jcol < 72) ? offw[jcol*64 + c] : ((jcol < 108) ? maskw[(jcol-72)*64 + c] : 0.f);
        womb[d3] = f2b(v);
      } else {
        int d4 = d - NBF_ZR - NBF_Q - NBF_OM;
        int nt = d4 / 1024, rem = d4 % 1024;
        int kc = rem / 512, rem2 = rem % 512;
        int ln = rem2 >> 3, j = rem2 & 7;
        int o = nt * 16 + (ln & 15);
        int c = kc * 32 + ((ln >> 4) << 3) + j;
        woutb[d4] = f2b(outw[o*64 + c]);
      }
      return;
    }
    float v;
    if (i < 20544) { v = 0.f; }
    else if (i < 20576) { v = gbz[i - OFF_BZ]; }
    else if (i < 39008) { v = 0.f; }
    else if (i < 39040) { v = gbr[i - OFF_BR]; }
    else if (i < 57472) { v = 0.f; }
    else if (i < 57504) { v = gbq[i - OFF_BQ]; }
    else if (i < 58080) { int d = i - OFF_DWP; int tap = d >> 6, o = d & 63; v = dww[o*9 + tap]; }
    else if (i < 58144) { v = dwb[i - OFF_DWB]; }
    else if (i < 58208) { v = lng[i - OFF_LNG]; }
    else if (i < 58272) { v = lnb[i - OFF_LNB]; }
    else if (i < 65184) { v = 0.f; }
    else if (i < 65292) { int j = i - OFF_OMB; v = (j < 72) ? offb[j] : maskb[j-72]; }
    else if (i < 65296) { v = 0.f; }
    else if (i < 69392) { int d = i - OFF_WINP; int c = d >> 6, o = d & 63; v = inpw[o*64 + c]; }
    else if (i < 69456) { v = inpb[i - OFF_BINP]; }
    else if (i < 73552) { v = 0.f; }
    else { v = outb[i - OFF_BOUT]; }
    Wp[i] = v;
    return;
  }

  // ===== encoder blocks =====
  int pb2 = b - NB_PREPB;
  int img = pb2 >> 8, h = (pb2 >> 1) & 127, w0 = (pb2 & 1) * 64;
  int px = tid & 63, sect = tid >> 6;
  #pragma unroll
  for (int k = 0; k < 8; ++k) {
    int i2 = k * 256 + tid;
    int c = i2 >> 5, o = i2 & 31;
    ewls[i2] = enc_w[o*64 + c];
  }
  if (tid < 32) {
    float sc = bn_g[tid] * rsqrtf(bn_v[tid] + 1e-5f);
    escl[tid] = sc;
    escl[32 + tid] = (enc_b[tid] - bn_m[tid]) * sc + bn_b[tid];
  }
  int hw = h * WT + w0 + px;
  const float* xp = X + (size_t)img * (64 * HWT) + hw;
  #pragma unroll
  for (int i2 = 0; i2 < 16; ++i2) {
    int c = sect * 16 + i2;
    xls[c * 64 + px] = xp[c * HWT];
  }
  const float* yp = Y + (size_t)img * (32 * HWT) + hw;
  bf16 yv[8];
  #pragma unroll
  for (int i2 = 0; i2 < 8; ++i2) yv[i2] = f2b(yp[(sect * 8 + i2) * HWT]);
  size_t pbb = (((size_t)img * 130 + h + 1) * 130 + (w0 + px + 1)) * 64;
  *(uint4*)(hxp + pbb + sect * 8) = *(const uint4*)yv;
  __syncthreads();
  float aen[8];
  #pragma unroll
  for (int o = 0; o < 8; ++o) aen[o] = 0.f;
  for (int k = 0; k < 64; ++k) {
    float a = xls[k * 64 + px];
    const float* we = ewls + k * 32 + sect * 8;
    #pragma unroll
    for (int o = 0; o < 8; ++o) aen[o] += a * we[o];
  }
  bf16 xe[8];
  #pragma unroll
  for (int o = 0; o < 8; ++o) {
    int oo = sect * 8 + o;
    float e = aen[o] * escl[oo] + escl[32 + oo];
    xe[o] = f2b(e / (1.f + __expf(-e)));
  }
  *(uint4*)(hxp + pbb + 32 + sect * 8) = *(const uint4*)xe;
  *(uint4*)(qinp + pbb + 32 + sect * 8) = *(const uint4*)xe;
}

// ---------------- K2: zrx = z+r GEMM blocks (512) + xl blocks img 0-1 (512) ----------------
__global__ void __launch_bounds__(256) k_zrx(
    const float* __restrict__ Wp,
    const bf16* __restrict__ hxp, const bf16* __restrict__ wzrb,
    bf16* __restrict__ qinp, bf16* __restrict__ zbuf,
    const float* __restrict__ X, bf16* __restrict__ xl) {
  __shared__ char sm[18688];
  int tid = threadIdx.x;
  int b = blockIdx.x;

  if (b < 512) {
    short* zt = (short*)sm;            // [32][132] = 8448 B
    short* ryt = (short*)(sm + 8448);  // [128][40] = 10240 B
    int wv = tid >> 6, ln = tid & 63;
    int quad = ln >> 4, lm = ln & 15;
    int img = b >> 7, h = b & 127;
    int p0 = wv * 32;
    const short* hs = (const short*)hxp;
    const short* ws = (const short*)wzrb;
    size_t rowb = ((size_t)img * 130 + h + 1) * 130;
    const short* ab0 = hs + (rowb + p0 + lm + 1) * 64 + quad * 8;
    const short* ab1 = ab0 + 16 * 64;
    short8v a0[18], a1[18];
    #pragma unroll
    for (int kc = 0; kc < 18; ++kc) {
      const int tap = kc >> 1, cin0 = (kc & 1) * 32;
      const int dd = (tap / 3 - 1) * 130 + (tap % 3 - 1);
      a0[kc] = *(const short8v*)(ab0 + dd * 64 + cin0);
      a1[kc] = *(const short8v*)(ab1 + dd * 64 + cin0);
    }
    float4v acc[8];
    #pragma unroll
    for (int t = 0; t < 8; ++t) acc[t] = (float4v){0.f, 0.f, 0.f, 0.f};
    #pragma unroll
    for (int kc = 0; kc < 18; ++kc) {
      #pragma unroll
      for (int t = 0; t < 4; ++t) {
        short8v bb = *(const short8v*)(ws + ((t * 18 + kc) * 64 + ln) * 8);
        acc[t*2]   = __builtin_amdgcn_mfma_f32_16x16x32_bf16(a0[kc], bb, acc[t*2], 0, 0, 0);
        acc[t*2+1] = __builtin_amdgcn_mfma_f32_16x16x32_bf16(a1[kc], bb, acc[t*2+1], 0, 0, 0);
      }
    }
    #pragma unroll
    for (int mt = 0; mt < 2; ++mt) {
      #pragma unroll
      for (int t = 0; t < 2; ++t) {
        int n = t * 16 + lm;
        float bz = Wp[OFF_BZ + n];
        short zp[4];
        #pragma unroll
        for (int ri = 0; ri < 4; ++ri)
          zp[ri] = f2bs(1.f / (1.f + __expf(-(acc[t*2+mt][ri] + bz))));
        *(short4v*)(zt + n * 132 + p0 + mt * 16 + quad * 4) = *(const short4v*)zp;
      }
    }
    #pragma unroll
    for (int mt = 0; mt < 2; ++mt) {
      #pragma unroll
      for (int t = 2; t < 4; ++t) {
        int c = (t - 2) * 16 + lm;
        float br = Wp[OFF_BR + c];
        #pragma unroll
        for (int ri = 0; ri < 4; ++ri) {
          int px = p0 + mt * 16 + quad * 4 + ri;
          float rv = 1.f / (1.f + __expf(-(acc[t*2+mt][ri] + br)));
          float yy = b2f(hxp[(rowb + px + 1) * 64 + c]);
          ryt[px * 40 + c] = f2bs(rv * yy);
        }
      }
    }
    __syncthreads();
    {
      int n2 = tid >> 3, pq = tid & 7;
      short8v z0 = *(const short8v*)(zt + n2 * 132 + pq * 16);
      short8v z1 = *(const short8v*)(zt + n2 * 132 + pq * 16 + 8);
      short* zo = (short*)zbuf + (((size_t)img * 128 + h) * 32 + n2) * 128 + pq * 16;
      *(short8v*)zo = z0;
      *(short8v*)(zo + 8) = z1;
    }
    {
      int px = tid >> 1, chalf = tid & 1;
      short8v r0 = *(const short8v*)(ryt + px * 40 + chalf * 16);
      short8v r1 = *(const short8v*)(ryt + px * 40 + chalf * 16 + 8);
      short* qo = (short*)qinp + (rowb + px + 1) * 64 + chalf * 16;
      *(short8v*)qo = r0;
      *(short8v*)(qo + 8) = r1;
    }
    return;
  }

  // ===== input linear via LDS x-tile, img 0-1 =====
  {
    float* xls = (float*)sm;
    int b2 = b - 512;
    int px = tid & 63, sect = tid >> 6;
    int img = b2 >> 8, h = (b2 >> 1) & 127, w0 = (b2 & 1) * 64;
    int hw = h * WT + w0 + px;
    const float* xp = X + (size_t)img * (64 * HWT) + hw;
    #pragma unroll
    for (int i = 0; i < 16; ++i) {
      int c = sect * 16 + i;
      xls[c * 64 + px] = xp[c * HWT];
    }
    __syncthreads();
    float acc[16];
    #pragma unroll
    for (int o = 0; o < 16; ++o) acc[o] = Wp[OFF_BINP + sect * 16 + o];
    for (int k = 0; k < 64; ++k) {
      float a = xls[k * 64 + px];
      const float* wr = Wp + OFF_WINP + k * 64 + sect * 16;
      #pragma unroll
      for (int o = 0; o < 16; ++o) acc[o] += a * wr[o];
    }
    bf16 ov[16];
    #pragma unroll
    for (int o = 0; o < 16; ++o) ov[o] = f2b(acc[o]);
    bf16* op = xl + ((size_t)img * HWT + hw) * 64 + sect * 16;
    ((uint4*)op)[0] = ((const uint4*)ov)[0];
    ((uint4*)op)[1] = ((const uint4*)ov)[1];
  }
}

// ---------------- K3: stageB = q-GEMM+combine blocks + xl blocks img 2-3 ----------------
__global__ void __launch_bounds__(256) k_stageB(
    const float* __restrict__ Y, const float* __restrict__ Wp,
    const bf16* __restrict__ qinp, const bf16* __restrict__ wqb,
    const bf16* __restrict__ zbuf, float* __restrict__ outh,
    const float* __restrict__ X, bf16* __restrict__ xl) {
  __shared__ char sm[16896];
  int tid = threadIdx.x;
  int b = blockIdx.x;

  if (b < 512) {
    float* hout = (float*)sm;   // [32][132]
    int wv = tid >> 6, ln = tid & 63;
    int quad = ln >> 4, lm = ln & 15;
    int img = b >> 7, h = b & 127;
    int p0 = wv * 32;
    const short* qs = (const short*)qinp;
    const short* ws = (const short*)wqb;
    size_t rowb = ((size_t)img * 130 + h + 1) * 130;
    const short* ab0 = qs + (rowb + p0 + lm + 1) * 64 + quad * 8;
    const short* ab1 = ab0 + 16 * 64;
    float4v acc[4];
    #pragma unroll
    for (int t = 0; t < 4; ++t) acc[t] = (float4v){0.f, 0.f, 0.f, 0.f};
    #pragma unroll
    for (int kc = 0; kc < 18; ++kc) {
      const int tap = kc >> 1, cin0 = (kc & 1) * 32;
      const int dd = (tap / 3 - 1) * 130 + (tap % 3 - 1);
      short8v a0 = *(const short8v*)(ab0 + dd * 64 + cin0);
      short8v a1 = *(const short8v*)(ab1 + dd * 64 + cin0);
      #pragma unroll
      for (int t = 0; t < 2; ++t) {
        short8v bb = *(const short8v*)(ws + ((t * 18 + kc) * 64 + ln) * 8);
        acc[t*2]   = __builtin_amdgcn_mfma_f32_16x16x32_bf16(a0, bb, acc[t*2], 0, 0, 0);
        acc[t*2+1] = __builtin_amdgcn_mfma_f32_16x16x32_bf16(a1, bb, acc[t*2+1], 0, 0, 0);
      }
    }
    #pragma unroll
    for (int mt = 0; mt < 2; ++mt) {
      #pragma unroll
      for (int t = 0; t < 2; ++t) {
        int n = t * 16 + lm;
        float bq = Wp[OFF_BQ + n];
        float4 hv;
        hv.x = acc[t*2+mt][0] + bq; hv.y = acc[t*2+mt][1] + bq;
        hv.z = acc[t*2+mt][2] + bq; hv.w = acc[t*2+mt][3] + bq;
        *(float4*)(hout + n * 132 + p0 + mt * 16 + quad * 4) = hv;
      }
    }
    __syncthreads();
    const short* zbb = (const short*)zbuf + ((size_t)img * 128 + h) * 32 * 128;
    #pragma unroll
    for (int r = 0; r < 4; ++r) {
      int n = (tid >> 5) + r * 8;
      int px4 = (tid & 31) * 4;
      float4 hv = *(const float4*)(hout + n * 132 + px4);
      uint2 zz = *(const uint2*)(zbb + n * 128 + px4);
      size_t gb = ((size_t)img * 32 + n) * HWT + h * 128 + px4;
      float4 yv = *(const float4*)(Y + gb);
      float z0 = bu2f((unsigned short)(zz.x & 0xFFFFu)), z1 = bu2f((unsigned short)(zz.x >> 16));
      float z2 = bu2f((unsigned short)(zz.y & 0xFFFFu)), z3 = bu2f((unsigned short)(zz.y >> 16));
      float4 o;
      o.x = (1.f - z0) * yv.x + z0 * tanhf(hv.x);
      o.y = (1.f - z1) * yv.y + z1 * tanhf(hv.y);
      o.z = (1.f - z2) * yv.z + z2 * tanhf(hv.z);
      o.w = (1.f - z3) * yv.w + z3 * tanhf(hv.w);
      *(float4*)(outh + gb) = o;
    }
    return;
  }

  // ===== input linear via LDS x-tile, img 2-3 =====
  {
    float* xls = (float*)sm;
    int b2 = b - 512;
    int px = tid & 63, sect = tid >> 6;
    int img = 2 + (b2 >> 8), h = (b2 >> 1) & 127, w0 = (b2 & 1) * 64;
    int hw = h * WT + w0 + px;
    const float* xp = X + (size_t)img * (64 * HWT) + hw;
    #pragma unroll
    for (int i = 0; i < 16; ++i) {
      int c = sect * 16 + i;
      xls[c * 64 + px] = xp[c * HWT];
    }
    __syncthreads();
    float acc[16];
    #pragma unroll
    for (int o = 0; o < 16; ++o) acc[o] = Wp[OFF_BINP + sect * 16 + o];
    for (int k = 0; k < 64; ++k) {
      float a = xls[k * 64 + px];
      const float* wr = Wp + OFF_WINP + k * 64 + sect * 16;
      #pragma unroll
      for (int o = 0; o < 16; ++o) acc[o] += a * wr[o];
    }
    bf16 ov[16];
    #pragma unroll
    for (int o = 0; o < 16; ++o) ov[o] = f2b(acc[o]);
    bf16* op = xl + ((size_t)img * HWT + hw) * 64 + sect * 16;
    ((uint4*)op)[0] = ((const uint4*)ov)[0];
    ((uint4*)op)[1] = ((const uint4*)ov)[1];
  }
}

// ---------------- K5 mega (512 thr, R13 best form) ----------------
#define LDS_PSA  0         // f32 [8][64]      2048
#define LDS_PSB  2048      // f32 [8][64]      2048
#define LDS_STAT 4096      // f32 [64][2]      512
#define LDS_Y    4608      // bf16 [64][72]    9216  (vls overlays after P2)
#define LDS_OM   13824     // bf16 [64][114]   14592
#define LDS_TOT  28416

__global__ void __launch_bounds__(512) k_mega(
    const float* __restrict__ Wp, const float* __restrict__ hb,
    const bf16* __restrict__ xl, const bf16* __restrict__ womb,
    const bf16* __restrict__ woutb, float* __restrict__ out0) {
  __shared__ char smem[LDS_TOT];
  float* psa  = (float*)(smem + LDS_PSA);
  float* psb  = (float*)(smem + LDS_PSB);
  float* stat = (float*)(smem + LDS_STAT);
  short* yls  = (short*)(smem + LDS_Y);
  short* omls = (short*)(smem + LDS_OM);
  short* vls  = (short*)(smem + LDS_Y);

  int tid = threadIdx.x;
  int img = blockIdx.z, h = blockIdx.y, w0 = blockIdx.x * 64;

  int wloc = tid & 63, part = tid >> 6;
  int w = w0 + wloc;
  float yv[8];
  {
    const float* hn = hb + (size_t)img * (32 * HWT);
    #pragma unroll
    for (int i = 0; i < 8; ++i) yv[i] = Wp[OFF_DWB + part*8 + i];
    #pragma unroll
    for (int tap = 0; tap < 9; ++tap) {
      int dy = tap / 3 - 1, dx = tap % 3 - 1;
      int hh = h + dy, ww = w + dx;
      bool ok = ((unsigned)hh < 128u) && ((unsigned)ww < 128u);
      int off = hh * WT + ww;
      #pragma unroll
      for (int j = 0; j < 4; ++j) {
        int cin = part * 4 + j;
        float a = ok ? hn[cin * HWT + off] : 0.f;
        yv[2*j]   += a * Wp[OFF_DWP + tap*64 + part*8 + 2*j];
        yv[2*j+1] += a * Wp[OFF_DWP + tap*64 + part*8 + 2*j+1];
      }
    }
  }
  float lsum = 0.f, lsq = 0.f;
  #pragma unroll
  for (int i = 0; i < 8; ++i) { lsum += yv[i]; lsq += yv[i]*yv[i]; }
  psa[part * 64 + wloc] = lsum;
  psb[part * 64 + wloc] = lsq;
  __syncthreads();
  if (tid < 64) {
    float s = 0.f, q = 0.f;
    #pragma unroll
    for (int p = 0; p < 8; ++p) { s += psa[p*64 + tid]; q += psb[p*64 + tid]; }
    float mu = s * (1.f/64.f);
    float var = q * (1.f/64.f) - mu * mu;
    stat[tid*2] = mu;
    stat[tid*2+1] = rsqrtf(var + 1e-6f);
  }
  __syncthreads();
  {
    float mu = stat[wloc*2], inv = stat[wloc*2+1];
    bf16 tmp[8];
    #pragma unroll
    for (int i = 0; i < 8; ++i) {
      int c = part*8 + i;
      float v = (yv[i] - mu) * inv * Wp[OFF_LNG + c] + Wp[OFF_LNB + c];
      tmp[i] = f2b(0.5f * v * (1.f + erff(v * 0.70710678118654752f)));
    }
    *(short8v*)(yls + wloc*72 + part*8) = *(const short8v*)tmp;
  }
  __syncthreads();

  int wv = tid >> 6, ln = tid & 63, quad = ln >> 4, lm = ln & 15;
  if (wv < 7) {
    const short* wb = (const short*)womb;
    float4v acc[4];
    #pragma unroll
    for (int mt = 0; mt < 4; ++mt) acc[mt] = (float4v){0.f,0.f,0.f,0.f};
    #pragma unroll
    for (int kc = 0; kc < 2; ++kc) {
      short8v b = *(const short8v*)(wb + ((wv * 2 + kc) * 64 + ln) * 8);
      #pragma unroll
      for (int mt = 0; mt < 4; ++mt) {
        short8v a = *(const short8v*)(yls + (mt*16 + lm)*72 + kc*32 + quad*8);
        acc[mt] = __builtin_amdgcn_mfma_f32_16x16x32_bf16(a, b, acc[mt], 0, 0, 0);
      }
    }
    float bias = Wp[OFF_OMB + wv*16 + lm];
    #pragma unroll
    for (int mt = 0; mt < 4; ++mt) {
      #pragma unroll
      for (int ri = 0; ri < 4; ++ri)
        omls[(mt*16 + quad*4 + ri)*114 + wv*16 + lm] = f2bs(acc[mt][ri] + bias);
    }
  }
  __syncthreads();

  {
    int px = tid >> 3, g = (tid >> 1) & 3, half = tid & 1;
    const short* oml = omls + px*114;
    float m[9];
    #pragma unroll
    for (int p = 0; p < 9; ++p) m[p] = bu2f((unsigned short)oml[72 + g*9 + p]);
    float mx = m[0];
    #pragma unroll
    for (int p = 1; p < 9; ++p) mx = fmaxf(mx, m[p]);
    float sum = 0.f;
    #pragma unroll
    for (int p = 0; p < 9; ++p) { m[p] = __expf(m[p] - mx); sum += m[p]; }
    float rs = 1.f / sum;
    int wg = w0 + px;
    const bf16* xn = xl + (size_t)img * (HWT * 64);
    float acc[8];
    #pragma unroll
    for (int i = 0; i < 8; ++i) acc[i] = 0.f;
    for (int p = 0; p < 9; ++p) {
      float bx = (float)(wg + p / 3 - 1);
      float by = (float)(h + p % 3 - 1);
      float ox = bu2f((unsigned short)oml[g*18 + p*2]);
      float oy = bu2f((unsigned short)oml[g*18 + p*2 + 1]);
      float mk = m[p] * rs;
      float pxx = bx + ox, pyy = by + oy;
      float fx = floorf(pxx), fy = floorf(pyy);
      int jx0 = (int)fx, jy0 = (int)fy;
      float wx1 = pxx - fx, wy1 = pyy - fy;
      float wx0 = 1.f - wx1, wy0 = 1.f - wy1;
      int cjx[4] = { jx0, jx0 + 1, jx0, jx0 + 1 };
      int cjy[4] = { jy0, jy0, jy0 + 1, jy0 + 1 };
      float cw[4] = { wx0*wy0, wx1*wy0, wx0*wy1, wx1*wy1 };
      #pragma unroll
      for (int k = 0; k < 4; ++k) {
        if ((unsigned)cjx[k] < 128u && (unsigned)cjy[k] < 128u) {
          float cf = mk * cw[k];
          const bf16* s = xn + (size_t)(cjy[k] * WT + cjx[k]) * 64 + g * 16 + half * 8;
          uint4 u0 = *(const uint4*)(s);
          const unsigned uu[4] = {u0.x,u0.y,u0.z,u0.w};
          #pragma unroll
          for (int q = 0; q < 4; ++q) {
            acc[2*q]     += cf * bu2f((unsigned short)(uu[q] & 0xFFFFu));
            acc[2*q + 1] += cf * bu2f((unsigned short)(uu[q] >> 16));
          }
        }
      }
    }
    bf16 tmp[8];
    #pragma unroll
    for (int i = 0; i < 8; ++i) tmp[i] = f2b(acc[i]);
    *(short8v*)(vls + px*72 + g*16 + half*8) = *(const short8v*)tmp;
  }
  __syncthreads();

  {
    const short* wb = (const short*)woutb;
    #pragma unroll
    for (int s = 0; s < 2; ++s) {
      int tile = wv * 2 + s;
      int nt = tile >> 2, mt = tile & 3;
      float4v acc = (float4v){0.f,0.f,0.f,0.f};
      #pragma unroll
      for (int kc = 0; kc < 2; ++kc) {
        short8v b = *(const short8v*)(wb + ((nt * 2 + kc) * 64 + ln) * 8);
        short8v a = *(const short8v*)(vls + (mt*16 + lm)*72 + kc*32 + quad*8);
        acc = __builtin_amdgcn_mfma_f32_16x16x32_bf16(a, b, acc, 0, 0, 0);
      }
      int ch = nt*16 + lm;
      float bias = Wp[OFF_BOUT + ch];
      float4 v;
      float s0 = acc[0] + bias; v.x = s0 / (1.f + __expf(-s0));
      float s1 = acc[1] + bias; v.y = s1 / (1.f + __expf(-s1));
      float s2 = acc[2] + bias; v.z = s2 / (1.f + __expf(-s2));
      float s3 = acc[3] + bias; v.w = s3 / (1.f + __expf(-s3));
      *(float4*)(out0 + ((size_t)img*64 + ch)*HWT + h*128 + w0 + mt*16 + quad*4) = v;
    }
  }
}

extern "C" void kernel_launch(void* const* d_in, const int* in_sizes, int n_in,
                              void* d_out, int out_size, void* d_ws, size_t ws_size,
                              hipStream_t stream) {
  const float* input_x = (const float*)d_in[0];
  const float* input_y = (const float*)d_in[1];

  float* Wp = (float*)d_ws;
  bf16* WZRB  = (bf16*)((char*)d_ws + B_WZRB);
  bf16* WQB   = (bf16*)((char*)d_ws + B_WQB);
  bf16* WOMB  = (bf16*)((char*)d_ws + B_WOMB);
  bf16* WOUTB = (bf16*)((char*)d_ws + B_WOUTB);
  bf16* HXP   = (bf16*)((char*)d_ws + B_HXP);
  bf16* QINP  = (bf16*)((char*)d_ws + B_QINP);
  bf16* ZBUF  = (bf16*)((char*)d_ws + B_ZBUF);
  bf16* XL    = (bf16*)((char*)d_ws + B_XL);
  float* out0 = (float*)d_out;
  float* outh = (float*)d_out + 4194304;

  k_stage1<<<dim3(NB_PREPB + 1024), dim3(256), 0, stream>>>(
      (const float*)d_in[2], (const float*)d_in[3], (const float*)d_in[4], (const float*)d_in[5],
      (const float*)d_in[6], (const float*)d_in[7], (const float*)d_in[8], (const float*)d_in[9],
      (const float*)d_in[10], (const float*)d_in[11], (const float*)d_in[12], (const float*)d_in[13],
      (const float*)d_in[14], (const float*)d_in[15], (const float*)d_in[16], (const float*)d_in[17],
      (const float*)d_in[18], (const float*)d_in[19], (const float*)d_in[20], (const float*)d_in[21],
      (const float*)d_in[22], (const float*)d_in[23], (const float*)d_in[24], (const float*)d_in[25],
      Wp, WZRB, WQB, WOMB, WOUTB, HXP, QINP, input_x, input_y);
  k_zrx<<<dim3(1024), dim3(256), 0, stream>>>(Wp, HXP, WZRB, QINP, ZBUF, input_x, XL);
  k_stageB<<<dim3(1024), dim3(256), 0, stream>>>(input_y, Wp, QINP, WQB, ZBUF, outh, input_x, XL);
  k_mega<<<dim3(2, 128, 4), dim3(512), 0, stream>>>(Wp, outh, XL, WOMB, WOUTB, out0);
}

// Round 17
// 243.366 us; speedup vs baseline: 1.0236x; 1.0020x over previous
//
#include <hip/hip_runtime.h>
#include <hip/hip_bf16.h>

typedef __hip_bfloat16 bf16;
typedef short short8v __attribute__((ext_vector_type(8)));
typedef short short4v __attribute__((ext_vector_type(4)));
typedef float float4v __attribute__((ext_vector_type(4)));

static __device__ __forceinline__ float b2f(bf16 v){ return __bfloat162float(v); }
static __device__ __forceinline__ bf16 f2b(float v){ return __float2bfloat16(v); }
static __device__ __forceinline__ float bu2f(unsigned short u){ return __uint_as_float(((unsigned)u) << 16); }
static __device__ __forceinline__ short f2bs(float v){ bf16 t = __float2bfloat16(v); return *(short*)&t; }

#define WT 128
#define HWT 16384

// ---- packed f32 weights (float offsets inside ws) ----
#define OFF_BZ    20544    // 32
#define OFF_BR    39008    // 32
#define OFF_BQ    57472    // 32
#define OFF_DWP   57504    // [tap][64]        576
#define OFF_DWB   58080    // 64
#define OFF_LNG   58144    // 64
#define OFF_LNB   58208    // 64
#define OFF_OMB   65184    // 108 (+4 zero pad)
#define OFF_WINP  65296    // [c][64]          4096
#define OFF_BINP  69392    // 64
#define OFF_BOUT  73552    // 64
#define NW_TOTAL  73616
#define NBF_ZR    36864    // bf16 fragment-order [t:4][kc:18][ln:64][j:8]
#define NBF_Q     18432    // bf16 fragment-order [t:2][kc:18][ln:64][j:8]
#define NBF_OM    7168     // bf16 fragment-order [wv:7][kc:2][ln:64][j:8]
#define NBF_OUT   4096     // bf16 fragment-order [nt:4][kc:2][ln:64][j:8]
#define NPREP     (NW_TOTAL + NBF_ZR + NBF_Q + NBF_OM + NBF_OUT)
#define NHALO     2064     // 4 imgs * 516 halo pixels
#define NTOT      (NPREP + NHALO)
#define NB_PREPB  556      // ceil(NTOT/256)

// ---- ws byte offsets (end = 21,928,448 B) ----
#define B_WZRB  294912
#define B_WQB   368640
#define B_WOMB  405504
#define B_WOUTB 419840
#define B_HXP   428544     // bf16 [4][130][130][64]  (dead after k_zr)
#define B_QINP  9081344    // bf16 [4][130][130][64]  (dead after stageB)
#define B_ZBUF  17734144   // bf16 [4][128][32][128]
#define B_XL    428544     // bf16 [4][HWT][64] overlays HXP (written in stageB, right before mega)

// ---------------- K1: stage1 = weight-prep blocks + encoder blocks (merged launch) ----------------
__global__ void __launch_bounds__(256) k_stage1(
    const float* __restrict__ enc_w, const float* __restrict__ enc_b,
    const float* __restrict__ bn_g, const float* __restrict__ bn_b,
    const float* __restrict__ bn_m, const float* __restrict__ bn_v,
    const float* __restrict__ gwz, const float* __restrict__ gbz,
    const float* __restrict__ gwr, const float* __restrict__ gbr,
    const float* __restrict__ gwq, const float* __restrict__ gbq,
    const float* __restrict__ dww, const float* __restrict__ dwb,
    const float* __restrict__ lng, const float* __restrict__ lnb,
    const float* __restrict__ offw, const float* __restrict__ offb,
    const float* __restrict__ maskw, const float* __restrict__ maskb,
    const float* __restrict__ inpw, const float* __restrict__ inpb,
    const float* __restrict__ outw, const float* __restrict__ outb,
    float* __restrict__ Wp, bf16* __restrict__ wzrb, bf16* __restrict__ wqb,
    bf16* __restrict__ womb, bf16* __restrict__ woutb,
    bf16* __restrict__ hxp, bf16* __restrict__ qinp,
    const float* __restrict__ X, const float* __restrict__ Y) {
  __shared__ float xls[4096];
  __shared__ float ewls[2048];
  __shared__ float escl[64];
  int tid = threadIdx.x;
  int b = blockIdx.x;

  if (b < NB_PREPB) {
    int i = b * 256 + tid;
    if (i >= NTOT) return;
    if (i >= NPREP) {
      int t = i - NPREP;
      int img = t / 516, r = t % 516;
      int ph, pw;
      if (r < 130) { ph = 0; pw = r; }
      else if (r < 260) { ph = 129; pw = r - 130; }
      else if (r < 388) { ph = r - 260 + 1; pw = 0; }
      else { ph = r - 388 + 1; pw = 129; }
      size_t pb = (((size_t)img * 130 + ph) * 130 + pw) * 64;
      uint4 zz = make_uint4(0, 0, 0, 0);
      #pragma unroll
      for (int k = 0; k < 8; ++k) {
        ((uint4*)(hxp + pb))[k] = zz;
        ((uint4*)(qinp + pb))[k] = zz;
      }
      return;
    }
    if (i >= NW_TOTAL) {
      int d = i - NW_TOTAL;
      if (d < NBF_ZR) {
        int t = d / 9216, rem = d % 9216;
        int kc = rem / 512, rem2 = rem % 512;
        int ln = rem2 >> 3, j = rem2 & 7;
        int n = t * 16 + (ln & 15);
        int cin = (kc & 1) * 32 + ((ln >> 4) << 3) + j;
        int tap = kc >> 1;
        float v = (n < 32) ? gwz[(n*64 + cin)*9 + tap] : gwr[((n-32)*64 + cin)*9 + tap];
        wzrb[d] = f2b(v);
      } else if (d < NBF_ZR + NBF_Q) {
        int d2 = d - NBF_ZR;
        int t = d2 / 9216, rem = d2 % 9216;
        int kc = rem / 512, rem2 = rem % 512;
        int ln = rem2 >> 3, j = rem2 & 7;
        int n = t * 16 + (ln & 15);
        int cin = (kc & 1) * 32 + ((ln >> 4) << 3) + j;
        int tap = kc >> 1;
        wqb[d2] = f2b(gwq[(n*64 + cin)*9 + tap]);
      } else if (d < NBF_ZR + NBF_Q + NBF_OM) {
        int d3 = d - NBF_ZR - NBF_Q;
        int wv = d3 / 1024, rem = d3 % 1024;
        int kc = rem / 512, rem2 = rem % 512;
        int ln = rem2 >> 3, j = rem2 & 7;
        int jcol = wv * 16 + (ln & 15);
        int c = kc * 32 + ((ln >> 4) << 3) + j;
        float v = (jcol < 72) ? offw[jcol*64 + c] : ((jcol < 108) ? maskw[(jcol-72)*64 + c] : 0.f);
        womb[d3] = f2b(v);
      } else {
        int d4 = d - NBF_ZR - NBF_Q - NBF_OM;
        int nt = d4 / 1024, rem = d4 % 1024;
        int kc = rem / 512, rem2 = rem % 512;
        int ln = rem2 >> 3, j = rem2 & 7;
        int o = nt * 16 + (ln & 15);
        int c = kc * 32 + ((ln >> 4) << 3) + j;
        woutb[d4] = f2b(outw[o*64 + c]);
      }
      return;
    }
    float v;
    if (i < 20544) { v = 0.f; }
    else if (i < 20576) { v = gbz[i - OFF_BZ]; }
    else if (i < 39008) { v = 0.f; }
    else if (i < 39040) { v = gbr[i - OFF_BR]; }
    else if (i < 57472) { v = 0.f; }
    else if (i < 57504) { v = gbq[i - OFF_BQ]; }
    else if (i < 58080) { int d = i - OFF_DWP; int tap = d >> 6, o = d & 63; v = dww[o*9 + tap]; }
    else if (i < 58144) { v = dwb[i - OFF_DWB]; }
    else if (i < 58208) { v = lng[i - OFF_LNG]; }
    else if (i < 58272) { v = lnb[i - OFF_LNB]; }
    else if (i < 65184) { v = 0.f; }
    else if (i < 65292) { int j = i - OFF_OMB; v = (j < 72) ? offb[j] : maskb[j-72]; }
    else if (i < 65296) { v = 0.f; }
    else if (i < 69392) { int d = i - OFF_WINP; int c = d >> 6, o = d & 63; v = inpw[o*64 + c]; }
    else if (i < 69456) { v = inpb[i - OFF_BINP]; }
    else if (i < 73552) { v = 0.f; }
    else { v = outb[i - OFF_BOUT]; }
    Wp[i] = v;
    return;
  }

  // ===== encoder blocks =====
  int pb2 = b - NB_PREPB;
  int img = pb2 >> 8, h = (pb2 >> 1) & 127, w0 = (pb2 & 1) * 64;
  int px = tid & 63, sect = tid >> 6;
  #pragma unroll
  for (int k = 0; k < 8; ++k) {
    int i2 = k * 256 + tid;
    int c = i2 >> 5, o = i2 & 31;
    ewls[i2] = enc_w[o*64 + c];
  }
  if (tid < 32) {
    float sc = bn_g[tid] * rsqrtf(bn_v[tid] + 1e-5f);
    escl[tid] = sc;
    escl[32 + tid] = (enc_b[tid] - bn_m[tid]) * sc + bn_b[tid];
  }
  int hw = h * WT + w0 + px;
  const float* xp = X + (size_t)img * (64 * HWT) + hw;
  #pragma unroll
  for (int i2 = 0; i2 < 16; ++i2) {
    int c = sect * 16 + i2;
    xls[c * 64 + px] = xp[c * HWT];
  }
  const float* yp = Y + (size_t)img * (32 * HWT) + hw;
  bf16 yv[8];
  #pragma unroll
  for (int i2 = 0; i2 < 8; ++i2) yv[i2] = f2b(yp[(sect * 8 + i2) * HWT]);
  size_t pbb = (((size_t)img * 130 + h + 1) * 130 + (w0 + px + 1)) * 64;
  *(uint4*)(hxp + pbb + sect * 8) = *(const uint4*)yv;
  __syncthreads();
  float aen[8];
  #pragma unroll
  for (int o = 0; o < 8; ++o) aen[o] = 0.f;
  for (int k = 0; k < 64; ++k) {
    float a = xls[k * 64 + px];
    const float* we = ewls + k * 32 + sect * 8;
    #pragma unroll
    for (int o = 0; o < 8; ++o) aen[o] += a * we[o];
  }
  bf16 xe[8];
  #pragma unroll
  for (int o = 0; o < 8; ++o) {
    int oo = sect * 8 + o;
    float e = aen[o] * escl[oo] + escl[32 + oo];
    xe[o] = f2b(e / (1.f + __expf(-e)));
  }
  *(uint4*)(hxp + pbb + 32 + sect * 8) = *(const uint4*)xe;
  *(uint4*)(qinp + pbb + 32 + sect * 8) = *(const uint4*)xe;
}

// ---------------- K2: z+r implicit-GEMM, M=32/wave, coalesced B (R11 best) ----------------
__global__ void __launch_bounds__(256) k_zr(
    const float* __restrict__ Wp,
    const bf16* __restrict__ hxp, const bf16* __restrict__ wzrb,
    bf16* __restrict__ qinp, bf16* __restrict__ zbuf) {
  __shared__ short zt[32 * 132];
  __shared__ short ryt[128 * 40];
  int tid = threadIdx.x;
  int wv = tid >> 6, ln = tid & 63;
  int quad = ln >> 4, lm = ln & 15;
  int img = blockIdx.z, h = blockIdx.y;
  int p0 = wv * 32;
  const short* hs = (const short*)hxp;
  const short* ws = (const short*)wzrb;
  size_t rowb = ((size_t)img * 130 + h + 1) * 130;
  const short* ab0 = hs + (rowb + p0 + lm + 1) * 64 + quad * 8;
  const short* ab1 = ab0 + 16 * 64;
  short8v a0[18], a1[18];
  #pragma unroll
  for (int kc = 0; kc < 18; ++kc) {
    const int tap = kc >> 1, cin0 = (kc & 1) * 32;
    const int dd = (tap / 3 - 1) * 130 + (tap % 3 - 1);
    a0[kc] = *(const short8v*)(ab0 + dd * 64 + cin0);
    a1[kc] = *(const short8v*)(ab1 + dd * 64 + cin0);
  }
  float4v acc[8];
  #pragma unroll
  for (int t = 0; t < 8; ++t) acc[t] = (float4v){0.f, 0.f, 0.f, 0.f};
  #pragma unroll
  for (int kc = 0; kc < 18; ++kc) {
    #pragma unroll
    for (int t = 0; t < 4; ++t) {
      short8v b = *(const short8v*)(ws + ((t * 18 + kc) * 64 + ln) * 8);
      acc[t*2]   = __builtin_amdgcn_mfma_f32_16x16x32_bf16(a0[kc], b, acc[t*2], 0, 0, 0);
      acc[t*2+1] = __builtin_amdgcn_mfma_f32_16x16x32_bf16(a1[kc], b, acc[t*2+1], 0, 0, 0);
    }
  }
  #pragma unroll
  for (int mt = 0; mt < 2; ++mt) {
    #pragma unroll
    for (int t = 0; t < 2; ++t) {
      int n = t * 16 + lm;
      float bz = Wp[OFF_BZ + n];
      short zp[4];
      #pragma unroll
      for (int ri = 0; ri < 4; ++ri)
        zp[ri] = f2bs(1.f / (1.f + __expf(-(acc[t*2+mt][ri] + bz))));
      *(short4v*)(zt + n * 132 + p0 + mt * 16 + quad * 4) = *(const short4v*)zp;
    }
  }
  #pragma unroll
  for (int mt = 0; mt < 2; ++mt) {
    #pragma unroll
    for (int t = 2; t < 4; ++t) {
      int c = (t - 2) * 16 + lm;
      float br = Wp[OFF_BR + c];
      #pragma unroll
      for (int ri = 0; ri < 4; ++ri) {
        int px = p0 + mt * 16 + quad * 4 + ri;
        float rv = 1.f / (1.f + __expf(-(acc[t*2+mt][ri] + br)));
        float yy = b2f(hxp[(rowb + px + 1) * 64 + c]);
        ryt[px * 40 + c] = f2bs(rv * yy);
      }
    }
  }
  __syncthreads();
  {
    int n2 = tid >> 3, pq = tid & 7;
    short8v z0 = *(const short8v*)(zt + n2 * 132 + pq * 16);
    short8v z1 = *(const short8v*)(zt + n2 * 132 + pq * 16 + 8);
    short* zo = (short*)zbuf + (((size_t)img * 128 + h) * 32 + n2) * 128 + pq * 16;
    *(short8v*)zo = z0;
    *(short8v*)(zo + 8) = z1;
  }
  {
    int px = tid >> 1, chalf = tid & 1;
    short8v r0 = *(const short8v*)(ryt + px * 40 + chalf * 16);
    short8v r1 = *(const short8v*)(ryt + px * 40 + chalf * 16 + 8);
    short* qo = (short*)qinp + (rowb + px + 1) * 64 + chalf * 16;
    *(short8v*)qo = r0;
    *(short8v*)(qo + 8) = r1;
  }
}

// ---------------- K3: stageB = q-GEMM+combine blocks + all input-linear blocks (R13 form) ----------------
__global__ void __launch_bounds__(256) k_stageB(
    const float* __restrict__ Y, const float* __restrict__ Wp,
    const bf16* __restrict__ qinp, const bf16* __restrict__ wqb,
    const bf16* __restrict__ zbuf, float* __restrict__ outh,
    const float* __restrict__ X, bf16* __restrict__ xl) {
  __shared__ char sm[16896];
  int tid = threadIdx.x;
  int b = blockIdx.x;

  if (b < 512) {
    float* hout = (float*)sm;   // [32][132]
    int wv = tid >> 6, ln = tid & 63;
    int quad = ln >> 4, lm = ln & 15;
    int img = b >> 7, h = b & 127;
    int p0 = wv * 32;
    const short* qs = (const short*)qinp;
    const short* ws = (const short*)wqb;
    size_t rowb = ((size_t)img * 130 + h + 1) * 130;
    const short* ab0 = qs + (rowb + p0 + lm + 1) * 64 + quad * 8;
    const short* ab1 = ab0 + 16 * 64;
    float4v acc[4];
    #pragma unroll
    for (int t = 0; t < 4; ++t) acc[t] = (float4v){0.f, 0.f, 0.f, 0.f};
    #pragma unroll
    for (int kc = 0; kc < 18; ++kc) {
      const int tap = kc >> 1, cin0 = (kc & 1) * 32;
      const int dd = (tap / 3 - 1) * 130 + (tap % 3 - 1);
      short8v a0 = *(const short8v*)(ab0 + dd * 64 + cin0);
      short8v a1 = *(const short8v*)(ab1 + dd * 64 + cin0);
      #pragma unroll
      for (int t = 0; t < 2; ++t) {
        short8v bb = *(const short8v*)(ws + ((t * 18 + kc) * 64 + ln) * 8);
        acc[t*2]   = __builtin_amdgcn_mfma_f32_16x16x32_bf16(a0, bb, acc[t*2], 0, 0, 0);
        acc[t*2+1] = __builtin_amdgcn_mfma_f32_16x16x32_bf16(a1, bb, acc[t*2+1], 0, 0, 0);
      }
    }
    #pragma unroll
    for (int mt = 0; mt < 2; ++mt) {
      #pragma unroll
      for (int t = 0; t < 2; ++t) {
        int n = t * 16 + lm;
        float bq = Wp[OFF_BQ + n];
        float4 hv;
        hv.x = acc[t*2+mt][0] + bq; hv.y = acc[t*2+mt][1] + bq;
        hv.z = acc[t*2+mt][2] + bq; hv.w = acc[t*2+mt][3] + bq;
        *(float4*)(hout + n * 132 + p0 + mt * 16 + quad * 4) = hv;
      }
    }
    __syncthreads();
    const short* zbb = (const short*)zbuf + ((size_t)img * 128 + h) * 32 * 128;
    #pragma unroll
    for (int r = 0; r < 4; ++r) {
      int n = (tid >> 5) + r * 8;
      int px4 = (tid & 31) * 4;
      float4 hv = *(const float4*)(hout + n * 132 + px4);
      uint2 zz = *(const uint2*)(zbb + n * 128 + px4);
      size_t gb = ((size_t)img * 32 + n) * HWT + h * 128 + px4;
      float4 yv = *(const float4*)(Y + gb);
      float z0 = bu2f((unsigned short)(zz.x & 0xFFFFu)), z1 = bu2f((unsigned short)(zz.x >> 16));
      float z2 = bu2f((unsigned short)(zz.y & 0xFFFFu)), z3 = bu2f((unsigned short)(zz.y >> 16));
      float4 o;
      o.x = (1.f - z0) * yv.x + z0 * tanhf(hv.x);
      o.y = (1.f - z1) * yv.y + z1 * tanhf(hv.y);
      o.z = (1.f - z2) * yv.z + z2 * tanhf(hv.z);
      o.w = (1.f - z3) * yv.w + z3 * tanhf(hv.w);
      *(float4*)(outh + gb) = o;
    }
    return;
  }

  // ===== input linear via LDS x-tile (all 4 imgs) =====
  {
    float* xls = (float*)sm;
    int b2 = b - 512;
    int px = tid & 63, sect = tid >> 6;
    int img = b2 >> 8, h = (b2 >> 1) & 127, w0 = (b2 & 1) * 64;
    int hw = h * WT + w0 + px;
    const float* xp = X + (size_t)img * (64 * HWT) + hw;
    #pragma unroll
    for (int i = 0; i < 16; ++i) {
      int c = sect * 16 + i;
      xls[c * 64 + px] = xp[c * HWT];
    }
    __syncthreads();
    float acc[16];
    #pragma unroll
    for (int o = 0; o < 16; ++o) acc[o] = Wp[OFF_BINP + sect * 16 + o];
    for (int k = 0; k < 64; ++k) {
      float a = xls[k * 64 + px];
      const float* wr = Wp + OFF_WINP + k * 64 + sect * 16;
      #pragma unroll
      for (int o = 0; o < 16; ++o) acc[o] += a * wr[o];
    }
    bf16 ov[16];
    #pragma unroll
    for (int o = 0; o < 16; ++o) ov[o] = f2b(acc[o]);
    bf16* op = xl + ((size_t)img * HWT + hw) * 64 + sect * 16;
    ((uint4*)op)[0] = ((const uint4*)ov)[0];
    ((uint4*)op)[1] = ((const uint4*)ov)[1];
  }
}

// ---------------- K5 mega (512 thr, R13 form) with XCD h-band swizzle ----------------
#define LDS_PSA  0         // f32 [8][64]      2048
#define LDS_PSB  2048      // f32 [8][64]      2048
#define LDS_STAT 4096      // f32 [64][2]      512
#define LDS_Y    4608      // bf16 [64][72]    9216  (vls overlays after P2)
#define LDS_OM   13824     // bf16 [64][114]   14592
#define LDS_TOT  28416

__global__ void __launch_bounds__(512) k_mega(
    const float* __restrict__ Wp, const float* __restrict__ hb,
    const bf16* __restrict__ xl, const bf16* __restrict__ womb,
    const bf16* __restrict__ woutb, float* __restrict__ out0) {
  __shared__ char smem[LDS_TOT];
  float* psa  = (float*)(smem + LDS_PSA);
  float* psb  = (float*)(smem + LDS_PSB);
  float* stat = (float*)(smem + LDS_STAT);
  short* yls  = (short*)(smem + LDS_Y);
  short* omls = (short*)(smem + LDS_OM);
  short* vls  = (short*)(smem + LDS_Y);

  int tid = threadIdx.x;
  // XCD h-band swizzle: consecutive ids round-robin XCDs; give each XCD a
  // contiguous 16-row h-band per image so halo/gather reuse stays in its L2.
  int bid = blockIdx.x;
  int xcd = bid & 7, slot = bid >> 3;            // slot 0..127
  int img = slot >> 5;                           // 4 imgs
  int rem = slot & 31;                           // 2 w-tiles x 16 h
  int h = xcd * 16 + (rem & 15);
  int w0 = (rem >> 4) * 64;

  int wloc = tid & 63, part = tid >> 6;
  int w = w0 + wloc;
  float yv[8];
  {
    const float* hn = hb + (size_t)img * (32 * HWT);
    #pragma unroll
    for (int i = 0; i < 8; ++i) yv[i] = Wp[OFF_DWB + part*8 + i];
    #pragma unroll
    for (int tap = 0; tap < 9; ++tap) {
      int dy = tap / 3 - 1, dx = tap % 3 - 1;
      int hh = h + dy, ww = w + dx;
      bool ok = ((unsigned)hh < 128u) && ((unsigned)ww < 128u);
      int off = hh * WT + ww;
      #pragma unroll
      for (int j = 0; j < 4; ++j) {
        int cin = part * 4 + j;
        float a = ok ? hn[cin * HWT + off] : 0.f;
        yv[2*j]   += a * Wp[OFF_DWP + tap*64 + part*8 + 2*j];
        yv[2*j+1] += a * Wp[OFF_DWP + tap*64 + part*8 + 2*j+1];
      }
    }
  }
  float lsum = 0.f, lsq = 0.f;
  #pragma unroll
  for (int i = 0; i < 8; ++i) { lsum += yv[i]; lsq += yv[i]*yv[i]; }
  psa[part * 64 + wloc] = lsum;
  psb[part * 64 + wloc] = lsq;
  __syncthreads();
  if (tid < 64) {
    float s = 0.f, q = 0.f;
    #pragma unroll
    for (int p = 0; p < 8; ++p) { s += psa[p*64 + tid]; q += psb[p*64 + tid]; }
    float mu = s * (1.f/64.f);
    float var = q * (1.f/64.f) - mu * mu;
    stat[tid*2] = mu;
    stat[tid*2+1] = rsqrtf(var + 1e-6f);
  }
  __syncthreads();
  {
    float mu = stat[wloc*2], inv = stat[wloc*2+1];
    bf16 tmp[8];
    #pragma unroll
    for (int i = 0; i < 8; ++i) {
      int c = part*8 + i;
      float v = (yv[i] - mu) * inv * Wp[OFF_LNG + c] + Wp[OFF_LNB + c];
      tmp[i] = f2b(0.5f * v * (1.f + erff(v * 0.70710678118654752f)));
    }
    *(short8v*)(yls + wloc*72 + part*8) = *(const short8v*)tmp;
  }
  __syncthreads();

  int wv = tid >> 6, ln = tid & 63, quad = ln >> 4, lm = ln & 15;
  if (wv < 7) {
    const short* wb = (const short*)womb;
    float4v acc[4];
    #pragma unroll
    for (int mt = 0; mt < 4; ++mt) acc[mt] = (float4v){0.f,0.f,0.f,0.f};
    #pragma unroll
    for (int kc = 0; kc < 2; ++kc) {
      short8v b = *(const short8v*)(wb + ((wv * 2 + kc) * 64 + ln) * 8);
      #pragma unroll
      for (int mt = 0; mt < 4; ++mt) {
        short8v a = *(const short8v*)(yls + (mt*16 + lm)*72 + kc*32 + quad*8);
        acc[mt] = __builtin_amdgcn_mfma_f32_16x16x32_bf16(a, b, acc[mt], 0, 0, 0);
      }
    }
    float bias = Wp[OFF_OMB + wv*16 + lm];
    #pragma unroll
    for (int mt = 0; mt < 4; ++mt) {
      #pragma unroll
      for (int ri = 0; ri < 4; ++ri)
        omls[(mt*16 + quad*4 + ri)*114 + wv*16 + lm] = f2bs(acc[mt][ri] + bias);
    }
  }
  __syncthreads();

  {
    int px = tid >> 3, g = (tid >> 1) & 3, half = tid & 1;
    const short* oml = omls + px*114;
    float m[9];
    #pragma unroll
    for (int p = 0; p < 9; ++p) m[p] = bu2f((unsigned short)oml[72 + g*9 + p]);
    float mx = m[0];
    #pragma unroll
    for (int p = 1; p < 9; ++p) mx = fmaxf(mx, m[p]);
    float sum = 0.f;
    #pragma unroll
    for (int p = 0; p < 9; ++p) { m[p] = __expf(m[p] - mx); sum += m[p]; }
    float rs = 1.f / sum;
    int wg = w0 + px;
    const bf16* xn = xl + (size_t)img * (HWT * 64);
    float acc[8];
    #pragma unroll
    for (int i = 0; i < 8; ++i) acc[i] = 0.f;
    for (int p = 0; p < 9; ++p) {
      float bx = (float)(wg + p / 3 - 1);
      float by = (float)(h + p % 3 - 1);
      float ox = bu2f((unsigned short)oml[g*18 + p*2]);
      float oy = bu2f((unsigned short)oml[g*18 + p*2 + 1]);
      float mk = m[p] * rs;
      float pxx = bx + ox, pyy = by + oy;
      float fx = floorf(pxx), fy = floorf(pyy);
      int jx0 = (int)fx, jy0 = (int)fy;
      float wx1 = pxx - fx, wy1 = pyy - fy;
      float wx0 = 1.f - wx1, wy0 = 1.f - wy1;
      int cjx[4] = { jx0, jx0 + 1, jx0, jx0 + 1 };
      int cjy[4] = { jy0, jy0, jy0 + 1, jy0 + 1 };
      float cw[4] = { wx0*wy0, wx1*wy0, wx0*wy1, wx1*wy1 };
      #pragma unroll
      for (int k = 0; k < 4; ++k) {
        if ((unsigned)cjx[k] < 128u && (unsigned)cjy[k] < 128u) {
          float cf = mk * cw[k];
          const bf16* s = xn + (size_t)(cjy[k] * WT + cjx[k]) * 64 + g * 16 + half * 8;
          uint4 u0 = *(const uint4*)(s);
          const unsigned uu[4] = {u0.x,u0.y,u0.z,u0.w};
          #pragma unroll
          for (int q = 0; q < 4; ++q) {
            acc[2*q]     += cf * bu2f((unsigned short)(uu[q] & 0xFFFFu));
            acc[2*q + 1] += cf * bu2f((unsigned short)(uu[q] >> 16));
          }
        }
      }
    }
    bf16 tmp[8];
    #pragma unroll
    for (int i = 0; i < 8; ++i) tmp[i] = f2b(acc[i]);
    *(short8v*)(vls + px*72 + g*16 + half*8) = *(const short8v*)tmp;
  }
  __syncthreads();

  {
    const short* wb = (const short*)woutb;
    #pragma unroll
    for (int s = 0; s < 2; ++s) {
      int tile = wv * 2 + s;
      int nt = tile >> 2, mt = tile & 3;
      float4v acc = (float4v){0.f,0.f,0.f,0.f};
      #pragma unroll
      for (int kc = 0; kc < 2; ++kc) {
        short8v b = *(const short8v*)(wb + ((nt * 2 + kc) * 64 + ln) * 8);
        short8v a = *(const short8v*)(vls + (mt*16 + lm)*72 + kc*32 + quad*8);
        acc = __builtin_amdgcn_mfma_f32_16x16x32_bf16(a, b, acc, 0, 0, 0);
      }
      int ch = nt*16 + lm;
      float bias = Wp[OFF_BOUT + ch];
      float4 v;
      float s0 = acc[0] + bias; v.x = s0 / (1.f + __expf(-s0));
      float s1 = acc[1] + bias; v.y = s1 / (1.f + __expf(-s1));
      float s2 = acc[2] + bias; v.z = s2 / (1.f + __expf(-s2));
      float s3 = acc[3] + bias; v.w = s3 / (1.f + __expf(-s3));
      *(float4*)(out0 + ((size_t)img*64 + ch)*HWT + h*128 + w0 + mt*16 + quad*4) = v;
    }
  }
}

extern "C" void kernel_launch(void* const* d_in, const int* in_sizes, int n_in,
                              void* d_out, int out_size, void* d_ws, size_t ws_size,
                              hipStream_t stream) {
  const float* input_x = (const float*)d_in[0];
  const float* input_y = (const float*)d_in[1];

  float* Wp = (float*)d_ws;
  bf16* WZRB  = (bf16*)((char*)d_ws + B_WZRB);
  bf16* WQB   = (bf16*)((char*)d_ws + B_WQB);
  bf16* WOMB  = (bf16*)((char*)d_ws + B_WOMB);
  bf16* WOUTB = (bf16*)((char*)d_ws + B_WOUTB);
  bf16* HXP   = (bf16*)((char*)d_ws + B_HXP);
  bf16* QINP  = (bf16*)((char*)d_ws + B_QINP);
  bf16* ZBUF  = (bf16*)((char*)d_ws + B_ZBUF);
  bf16* XL    = (bf16*)((char*)d_ws + B_XL);
  float* out0 = (float*)d_out;
  float* outh = (float*)d_out + 4194304;

  k_stage1<<<dim3(NB_PREPB + 1024), dim3(256), 0, stream>>>(
      (const float*)d_in[2], (const float*)d_in[3], (const float*)d_in[4], (const float*)d_in[5],
      (const float*)d_in[6], (const float*)d_in[7], (const float*)d_in[8], (const float*)d_in[9],
      (const float*)d_in[10], (const float*)d_in[11], (const float*)d_in[12], (const float*)d_in[13],
      (const float*)d_in[14], (const float*)d_in[15], (const float*)d_in[16], (const float*)d_in[17],
      (const float*)d_in[18], (const float*)d_in[19], (const float*)d_in[20], (const float*)d_in[21],
      (const float*)d_in[22], (const float*)d_in[23], (const float*)d_in[24], (const float*)d_in[25],
      Wp, WZRB, WQB, WOMB, WOUTB, HXP, QINP, input_x, input_y);
  k_zr<<<dim3(1, 128, 4), dim3(256), 0, stream>>>(Wp, HXP, WZRB, QINP, ZBUF);
  k_stageB<<<dim3(1536), dim3(256), 0, stream>>>(input_y, Wp, QINP, WQB, ZBUF, outh, input_x, XL);
  k_mega<<<dim3(1024), dim3(512), 0, stream>>>(Wp, outh, XL, WOMB, WOUTB, out0);
}